// Round 2
// baseline (62998.132 us; speedup 1.0000x reference)
//
#include <hip/hip_runtime.h>
#include <math.h>

// Problem constants
#define NROWS 16384      // B*H*W = 16*32*32
#define NCODES 8192
#define DIMS 256

// ws layout (float offsets)
#define OFF_WN   0u          // 8192*256
#define OFF_W2   2097152u    // 8192
#define OFF_ZN   2105344u    // 16384*256
#define OFF_RM   6299648u    // 16384 row max-logit
#define OFF_RS   6316032u    // 16384 row sum-exp
#define OFF_RIDX 6332416u    // 16384 argmax index (int)
#define OFF_AVGP 6348800u    // 8192 avg_probs accumulator
#define OFF_SCAL 6356992u    // [0]=cb_sum [1]=ent_sum

// GEMM tiling
#define BM 128
#define BN 128
#define BK 32
#define LSTR 36   // padded LDS row stride (floats); 36*4=144B is 16B aligned

__global__ __launch_bounds__(256) void k0_init(float* ws) {
  int i = blockIdx.x * 256 + threadIdx.x;
  if (i < NCODES) ws[OFF_AVGP + i] = 0.f;
  if (i < 8) ws[OFF_SCAL + i] = 0.f;
}

// weight = emb @ proj_w^T + b ; wn = normalize(weight); w2 = sum(wn^2)
__global__ __launch_bounds__(256) void k1_codebook(const float* __restrict__ emb,
    const float* __restrict__ pw, const float* __restrict__ pb,
    float* __restrict__ wn, float* __restrict__ w2) {
  __shared__ float e[256];
  __shared__ float red[256];
  int k = blockIdx.x, t = threadIdx.x;
  e[t] = emb[(size_t)k * 256 + t];
  __syncthreads();
  const float4* prow = reinterpret_cast<const float4*>(pw + (size_t)t * 256);
  float acc = pb[t];
  #pragma unroll 8
  for (int q = 0; q < 64; ++q) {
    float4 p4 = prow[q];
    acc += e[q*4+0]*p4.x + e[q*4+1]*p4.y + e[q*4+2]*p4.z + e[q*4+3]*p4.w;
  }
  red[t] = acc * acc;
  __syncthreads();
  for (int s = 128; s; s >>= 1) { if (t < s) red[t] += red[t+s]; __syncthreads(); }
  float inv = 1.f / fmaxf(sqrtf(red[0]), 1e-6f);
  float v = acc * inv;
  wn[(size_t)k*256 + t] = v;
  __syncthreads();
  red[t] = v * v;
  __syncthreads();
  for (int s = 128; s; s >>= 1) { if (t < s) red[t] += red[t+s]; __syncthreads(); }
  if (t == 0) w2[k] = red[0];
}

// zn = normalize over channel dim; z is [B,C,H,W], zn is [row=(b*H+h)*W+w][C]
__global__ __launch_bounds__(256) void k2_zn(const float* __restrict__ z,
                                             float* __restrict__ zn) {
  __shared__ float tile[256][33];
  __shared__ float inv[32];
  int bh = blockIdx.x, t = threadIdx.x;
  const float* zb = z + (size_t)(bh >> 5) * (256*1024) + (size_t)(bh & 31) * 32;
  for (int j = 0; j < 32; ++j) {
    int i = t + j*256; int c = i >> 5, w = i & 31;
    tile[c][w] = zb[(size_t)c*1024 + w];
  }
  __syncthreads();
  if (t < 32) {
    float s = 0.f;
    for (int c = 0; c < 256; ++c) { float v = tile[c][t]; s += v*v; }
    inv[t] = 1.f / fmaxf(sqrtf(s), 1e-6f);
  }
  __syncthreads();
  float* znp = zn + (size_t)bh * 32 * 256;
  for (int w = 0; w < 32; ++w) znp[(size_t)w*256 + t] = tile[t][w] * inv[w];
}

// Pass 1: per-row online (max logit, sum exp, argmax). logit = 200*dot - 100*w2[k]
__global__ __launch_bounds__(256, 4) void k3_pass1(const float* __restrict__ zn,
    const float* __restrict__ wn, const float* __restrict__ w2,
    float* __restrict__ row_m, float* __restrict__ row_S, int* __restrict__ row_idx) {
  __shared__ __align__(16) float A[BM*LSTR];
  __shared__ __align__(16) float Bt[BN*LSTR];
  __shared__ float w2s[BN];
  __shared__ float m_s[BM], S_s[BM];
  __shared__ int k_s[BM];
  int t = threadIdx.x;
  int tx = t & 15, ty = t >> 4;
  int r0 = blockIdx.x * BM;
  if (t < BM) { m_s[t] = -1e30f; S_s[t] = 0.f; k_s[t] = 0x7fffffff; }
  for (int kb = 0; kb < NCODES; kb += BN) {
    __syncthreads();
    if (t < BN) w2s[t] = w2[kb + t];
    float acc[8][8];
    #pragma unroll
    for (int i = 0; i < 8; ++i)
      #pragma unroll
      for (int j = 0; j < 8; ++j) acc[i][j] = 0.f;
    for (int dc = 0; dc < DIMS; dc += BK) {
      __syncthreads();
      #pragma unroll
      for (int s = 0; s < 4; ++s) {
        int p = t + s*256; int r = p >> 3, q = p & 7;
        *reinterpret_cast<float4*>(&A[r*LSTR + q*4]) =
          *reinterpret_cast<const float4*>(zn + (size_t)(r0 + r)*256 + dc + q*4);
      }
      #pragma unroll
      for (int s = 0; s < 4; ++s) {
        int p = t + s*256; int r = p >> 3, q = p & 7;
        *reinterpret_cast<float4*>(&Bt[r*LSTR + q*4]) =
          *reinterpret_cast<const float4*>(wn + (size_t)(kb + r)*256 + dc + q*4);
      }
      __syncthreads();
      #pragma unroll
      for (int d = 0; d < BK; d += 4) {
        float4 a4[8];
        #pragma unroll
        for (int i = 0; i < 8; ++i)
          a4[i] = *reinterpret_cast<const float4*>(&A[(ty + 16*i)*LSTR + d]);
        #pragma unroll
        for (int j = 0; j < 8; ++j) {
          float4 b4 = *reinterpret_cast<const float4*>(&Bt[(tx + 16*j)*LSTR + d]);
          #pragma unroll
          for (int i = 0; i < 8; ++i)
            acc[i][j] += a4[i].x*b4.x + a4[i].y*b4.y + a4[i].z*b4.z + a4[i].w*b4.w;
        }
      }
    }
    // stats merge
    #pragma unroll
    for (int i = 0; i < 8; ++i) {
      float l[8];
      float m = -1e30f; int bk_ = 0x7fffffff;
      #pragma unroll
      for (int j = 0; j < 8; ++j) {
        int k = tx + 16*j;
        l[j] = 200.f*acc[i][j] - 100.f*w2s[k];
        if (l[j] > m) { m = l[j]; bk_ = kb + k; }
        else if (l[j] == m && (kb + k) < bk_) { bk_ = kb + k; }
      }
      float S = 0.f;
      #pragma unroll
      for (int j = 0; j < 8; ++j) S += expf(l[j] - m);
      #pragma unroll
      for (int mask = 1; mask < 16; mask <<= 1) {
        float om = __shfl_xor(m, mask, 64);
        float oS = __shfl_xor(S, mask, 64);
        int   ok = __shfl_xor(bk_, mask, 64);
        float mm = fmaxf(m, om);
        S = S * expf(m - mm) + oS * expf(om - mm);
        if (om > m || (om == m && ok < bk_)) bk_ = ok;
        m = mm;
      }
      if (tx == 0) {
        int r = ty + 16*i;
        float gm = m_s[r], gS = S_s[r]; int gk = k_s[r];
        float mm = fmaxf(gm, m);
        S_s[r] = gS * expf(gm - mm) + S * expf(m - mm);
        if (m > gm || (m == gm && bk_ < gk)) k_s[r] = bk_;
        m_s[r] = mm;
      }
    }
  }
  __syncthreads();
  if (t < BM) {
    row_m[r0 + t] = m_s[t];
    row_S[r0 + t] = S_s[t];
    row_idx[r0 + t] = k_s[t];
  }
}

// Pass 2: recompute logits, accumulate avg_probs and sample entropy
__global__ __launch_bounds__(256, 4) void k4_pass2(const float* __restrict__ zn,
    const float* __restrict__ wn, const float* __restrict__ w2,
    const float* __restrict__ row_m, const float* __restrict__ row_S,
    float* __restrict__ avg_probs, float* __restrict__ scal) {
  __shared__ __align__(16) float A[BM*LSTR];
  __shared__ __align__(16) float Bt[BN*LSTR];
  __shared__ float w2s[BN];
  __shared__ float colsum[16][BN];
  __shared__ float st_m[BM], st_invS[BM], st_mls[BM];
  __shared__ float red[256];
  int t = threadIdx.x;
  int tx = t & 15, ty = t >> 4;
  int r0 = blockIdx.x * BM;
  if (t < BM) {
    float m = row_m[r0 + t], S = row_S[r0 + t];
    st_m[t] = m; st_invS[t] = 1.f / S; st_mls[t] = m + logf(S);
  }
  float ent_acc = 0.f;
  for (int kb = 0; kb < NCODES; kb += BN) {
    __syncthreads();
    if (t < BN) w2s[t] = w2[kb + t];
    float acc[8][8];
    #pragma unroll
    for (int i = 0; i < 8; ++i)
      #pragma unroll
      for (int j = 0; j < 8; ++j) acc[i][j] = 0.f;
    for (int dc = 0; dc < DIMS; dc += BK) {
      __syncthreads();
      #pragma unroll
      for (int s = 0; s < 4; ++s) {
        int p = t + s*256; int r = p >> 3, q = p & 7;
        *reinterpret_cast<float4*>(&A[r*LSTR + q*4]) =
          *reinterpret_cast<const float4*>(zn + (size_t)(r0 + r)*256 + dc + q*4);
      }
      #pragma unroll
      for (int s = 0; s < 4; ++s) {
        int p = t + s*256; int r = p >> 3, q = p & 7;
        *reinterpret_cast<float4*>(&Bt[r*LSTR + q*4]) =
          *reinterpret_cast<const float4*>(wn + (size_t)(kb + r)*256 + dc + q*4);
      }
      __syncthreads();
      #pragma unroll
      for (int d = 0; d < BK; d += 4) {
        float4 a4[8];
        #pragma unroll
        for (int i = 0; i < 8; ++i)
          a4[i] = *reinterpret_cast<const float4*>(&A[(ty + 16*i)*LSTR + d]);
        #pragma unroll
        for (int j = 0; j < 8; ++j) {
          float4 b4 = *reinterpret_cast<const float4*>(&Bt[(tx + 16*j)*LSTR + d]);
          #pragma unroll
          for (int i = 0; i < 8; ++i)
            acc[i][j] += a4[i].x*b4.x + a4[i].y*b4.y + a4[i].z*b4.z + a4[i].w*b4.w;
        }
      }
    }
    float ps[8];
    #pragma unroll
    for (int j = 0; j < 8; ++j) ps[j] = 0.f;
    #pragma unroll
    for (int i = 0; i < 8; ++i) {
      int r = ty + 16*i;
      float m = st_m[r], invS = st_invS[r], mls = st_mls[r];
      #pragma unroll
      for (int j = 0; j < 8; ++j) {
        int k = tx + 16*j;
        float l = 200.f*acc[i][j] - 100.f*w2s[k];
        float p = expf(l - m) * invS;
        ent_acc -= p * (l - mls);
        ps[j] += p;
      }
    }
    __syncthreads();
    #pragma unroll
    for (int j = 0; j < 8; ++j) colsum[ty][tx + 16*j] = ps[j];
    __syncthreads();
    if (t < BN) {
      float s = 0.f;
      #pragma unroll
      for (int yy = 0; yy < 16; ++yy) s += colsum[yy][t];
      atomicAdd(&avg_probs[kb + t], s * (1.f/16384.f));
    }
  }
  __syncthreads();
  red[t] = ent_acc;
  __syncthreads();
  for (int s = 128; s; s >>= 1) { if (t < s) red[t] += red[t+s]; __syncthreads(); }
  if (t == 0) atomicAdd(&scal[1], red[0]);
}

// gather q = wn[idx], codebook loss, write z_q channel-first
__global__ __launch_bounds__(256) void k5_gather(const float* __restrict__ zn,
    const float* __restrict__ wn, const int* __restrict__ row_idx,
    float* __restrict__ out_zq, float* __restrict__ scal) {
  __shared__ float tile[256][33];
  __shared__ float red4[4];
  __shared__ float red[256];
  int bh = blockIdx.x, t = threadIdx.x;
  int b = bh >> 5, h = bh & 31;
  float cb = 0.f;
  for (int w = 0; w < 32; ++w) {
    int r = bh*32 + w;
    int idx = row_idx[r];
    float q = wn[(size_t)idx*256 + t];
    float s = q*q;
    #pragma unroll
    for (int mask = 32; mask; mask >>= 1) s += __shfl_xor(s, mask, 64);
    if ((t & 63) == 0) red4[t >> 6] = s;
    __syncthreads();
    float tot = red4[0] + red4[1] + red4[2] + red4[3];
    float inv = 1.f / fmaxf(sqrtf(tot), 1e-6f);
    float zv = zn[(size_t)r*256 + t];
    float d = q*inv - zv;
    cb += d*d;
    tile[t][w] = q;
    __syncthreads();
  }
  red[t] = cb;
  __syncthreads();
  for (int s2 = 128; s2; s2 >>= 1) { if (t < s2) red[t] += red[t+s2]; __syncthreads(); }
  if (t == 0) atomicAdd(&scal[0], red[0]);
  float* ob = out_zq + (size_t)b*256*1024 + (size_t)h*32;
  for (int j = 0; j < 32; ++j) {
    int i = t + j*256; int c = i >> 5, ww = i & 31;
    ob[(size_t)c*1024 + ww] = tile[c][ww];
  }
}

// finalize scalars + emit indices as float
__global__ __launch_bounds__(256) void k6_final(const float* __restrict__ avg_probs,
    const float* __restrict__ scal, const int* __restrict__ row_idx,
    float* __restrict__ out) {
  int t = threadIdx.x;
  if (blockIdx.x < 64) {
    int r = blockIdx.x*256 + t;
    out[4194307 + r] = (float)row_idx[r];
    return;
  }
  __shared__ float red[256];
  float s = 0.f;
  for (int j = 0; j < 32; ++j) {
    float v = avg_probs[t + j*256];
    s -= v * logf(v + 1e-5f);
  }
  red[t] = s;
  __syncthreads();
  for (int q = 128; q; q >>= 1) { if (t < q) red[t] += red[t+q]; __syncthreads(); }
  if (t == 0) {
    float avg_entropy = red[0];
    float sample_entropy = scal[1] * (1.f/16384.f);
    float cb = scal[0] * (1.f/4194304.f);
    out[4194304] = cb;
    out[4194305] = 0.25f * cb;
    out[4194306] = 0.1f * (sample_entropy - avg_entropy);
  }
}

extern "C" void kernel_launch(void* const* d_in, const int* in_sizes, int n_in,
                              void* d_out, int out_size, void* d_ws, size_t ws_size,
                              hipStream_t stream) {
  const float* z   = (const float*)d_in[0];
  const float* emb = (const float*)d_in[1];
  const float* pw  = (const float*)d_in[2];
  const float* pb  = (const float*)d_in[3];
  float* ws  = (float*)d_ws;
  float* out = (float*)d_out;
  float* wn   = ws + OFF_WN;
  float* w2   = ws + OFF_W2;
  float* zn   = ws + OFF_ZN;
  float* rm   = ws + OFF_RM;
  float* rS   = ws + OFF_RS;
  int*   ridx = (int*)(ws + OFF_RIDX);
  float* avgp = ws + OFF_AVGP;
  float* scal = ws + OFF_SCAL;

  k0_init<<<32, 256, 0, stream>>>(ws);
  k1_codebook<<<NCODES, 256, 0, stream>>>(emb, pw, pb, wn, w2);
  k2_zn<<<512, 256, 0, stream>>>(z, zn);
  k3_pass1<<<NROWS/BM, 256, 0, stream>>>(zn, wn, w2, rm, rS, ridx);
  k4_pass2<<<NROWS/BM, 256, 0, stream>>>(zn, wn, w2, rm, rS, avgp, scal);
  k5_gather<<<512, 256, 0, stream>>>(zn, wn, ridx, out, scal);
  k6_final<<<65, 256, 0, stream>>>(avgp, scal, ridx, out);
}

// Round 3
// 45463.062 us; speedup vs baseline: 1.3857x; 1.3857x over previous
//
#include <hip/hip_runtime.h>
#include <math.h>

// Problem constants
#define NROWS 16384      // B*H*W = 16*32*32
#define NCODES 8192
#define DIMS 256

// ws layout (float offsets)
#define OFF_WN   0u          // 8192*256
#define OFF_W2   2097152u    // 8192
#define OFF_ZN   2105344u    // 16384*256
#define OFF_RM   6299648u    // 16384 row max-logit
#define OFF_RS   6316032u    // 16384 row sum-exp
#define OFF_RIDX 6332416u    // 16384 argmax index (int)
#define OFF_AVGP 6348800u    // 8192 avg_probs accumulator
#define OFF_SCAL 6356992u    // [0]=cb_sum [1]=ent_sum

// GEMM tiling
#define BM 128
#define BN 128
#define BK 32
#define LSTR 36   // padded LDS row stride (floats); 36*4=144B is 16B aligned

__global__ __launch_bounds__(256) void k0_init(float* ws) {
  int i = blockIdx.x * 256 + threadIdx.x;
  if (i < NCODES) ws[OFF_AVGP + i] = 0.f;
  if (i < 8) ws[OFF_SCAL + i] = 0.f;
}

// weight = emb @ proj_w^T + b ; wn = normalize(weight); w2 = sum(wn^2)
__global__ __launch_bounds__(256) void k1_codebook(const float* __restrict__ emb,
    const float* __restrict__ pw, const float* __restrict__ pb,
    float* __restrict__ wn, float* __restrict__ w2) {
  __shared__ float e[256];
  __shared__ float red[256];
  int k = blockIdx.x, t = threadIdx.x;
  e[t] = emb[(size_t)k * 256 + t];
  __syncthreads();
  const float4* prow = reinterpret_cast<const float4*>(pw + (size_t)t * 256);
  float acc = pb[t];
  #pragma unroll 8
  for (int q = 0; q < 64; ++q) {
    float4 p4 = prow[q];
    acc += e[q*4+0]*p4.x + e[q*4+1]*p4.y + e[q*4+2]*p4.z + e[q*4+3]*p4.w;
  }
  red[t] = acc * acc;
  __syncthreads();
  for (int s = 128; s; s >>= 1) { if (t < s) red[t] += red[t+s]; __syncthreads(); }
  float inv = 1.f / fmaxf(sqrtf(red[0]), 1e-6f);
  float v = acc * inv;
  wn[(size_t)k*256 + t] = v;
  __syncthreads();
  red[t] = v * v;
  __syncthreads();
  for (int s = 128; s; s >>= 1) { if (t < s) red[t] += red[t+s]; __syncthreads(); }
  if (t == 0) w2[k] = red[0];
}

// zn = normalize over channel dim; z is [B,C,H,W], zn is [row=(b*H+h)*W+w][C]
__global__ __launch_bounds__(256) void k2_zn(const float* __restrict__ z,
                                             float* __restrict__ zn) {
  __shared__ float tile[256][33];
  __shared__ float inv[32];
  int bh = blockIdx.x, t = threadIdx.x;
  const float* zb = z + (size_t)(bh >> 5) * (256*1024) + (size_t)(bh & 31) * 32;
  for (int j = 0; j < 32; ++j) {
    int i = t + j*256; int c = i >> 5, w = i & 31;
    tile[c][w] = zb[(size_t)c*1024 + w];
  }
  __syncthreads();
  if (t < 32) {
    float s = 0.f;
    for (int c = 0; c < 256; ++c) { float v = tile[c][t]; s += v*v; }
    inv[t] = 1.f / fmaxf(sqrtf(s), 1e-6f);
  }
  __syncthreads();
  float* znp = zn + (size_t)bh * 32 * 256;
  for (int w = 0; w < 32; ++w) znp[(size_t)w*256 + t] = tile[t][w] * inv[w];
}

// Pass 1: per-row online (max logit, sum exp, argmax). logit = 200*dot - 100*w2[k]
// launch_bounds(256,2): min 2 waves/EU -> 256-VGPR budget. (256,4) capped the
// allocator at 128 and it spilled acc[8][8] to scratch: 48 GB/dispatch scratch
// writes, VALUBusy 1.6%, 55 ms. See round-2 counters.
__global__ __launch_bounds__(256, 2) void k3_pass1(const float* __restrict__ zn,
    const float* __restrict__ wn, const float* __restrict__ w2,
    float* __restrict__ row_m, float* __restrict__ row_S, int* __restrict__ row_idx) {
  __shared__ __align__(16) float A[BM*LSTR];
  __shared__ __align__(16) float Bt[BN*LSTR];
  __shared__ float w2s[BN];
  __shared__ float m_s[BM], S_s[BM];
  __shared__ int k_s[BM];
  int t = threadIdx.x;
  int tx = t & 15, ty = t >> 4;
  int r0 = blockIdx.x * BM;
  if (t < BM) { m_s[t] = -1e30f; S_s[t] = 0.f; k_s[t] = 0x7fffffff; }
  for (int kb = 0; kb < NCODES; kb += BN) {
    __syncthreads();
    if (t < BN) w2s[t] = w2[kb + t];
    float acc[8][8];
    #pragma unroll
    for (int i = 0; i < 8; ++i)
      #pragma unroll
      for (int j = 0; j < 8; ++j) acc[i][j] = 0.f;
    for (int dc = 0; dc < DIMS; dc += BK) {
      __syncthreads();
      #pragma unroll
      for (int s = 0; s < 4; ++s) {
        int p = t + s*256; int r = p >> 3, q = p & 7;
        *reinterpret_cast<float4*>(&A[r*LSTR + q*4]) =
          *reinterpret_cast<const float4*>(zn + (size_t)(r0 + r)*256 + dc + q*4);
      }
      #pragma unroll
      for (int s = 0; s < 4; ++s) {
        int p = t + s*256; int r = p >> 3, q = p & 7;
        *reinterpret_cast<float4*>(&Bt[r*LSTR + q*4]) =
          *reinterpret_cast<const float4*>(wn + (size_t)(kb + r)*256 + dc + q*4);
      }
      __syncthreads();
      #pragma unroll
      for (int d = 0; d < BK; d += 4) {
        float4 a4[8];
        #pragma unroll
        for (int i = 0; i < 8; ++i)
          a4[i] = *reinterpret_cast<const float4*>(&A[(ty + 16*i)*LSTR + d]);
        #pragma unroll
        for (int j = 0; j < 8; ++j) {
          float4 b4 = *reinterpret_cast<const float4*>(&Bt[(tx + 16*j)*LSTR + d]);
          #pragma unroll
          for (int i = 0; i < 8; ++i)
            acc[i][j] += a4[i].x*b4.x + a4[i].y*b4.y + a4[i].z*b4.z + a4[i].w*b4.w;
        }
      }
    }
    // stats merge
    #pragma unroll
    for (int i = 0; i < 8; ++i) {
      float l[8];
      float m = -1e30f; int bk_ = 0x7fffffff;
      #pragma unroll
      for (int j = 0; j < 8; ++j) {
        int k = tx + 16*j;
        l[j] = 200.f*acc[i][j] - 100.f*w2s[k];
        if (l[j] > m) { m = l[j]; bk_ = kb + k; }
        else if (l[j] == m && (kb + k) < bk_) { bk_ = kb + k; }
      }
      float S = 0.f;
      #pragma unroll
      for (int j = 0; j < 8; ++j) S += expf(l[j] - m);
      #pragma unroll
      for (int mask = 1; mask < 16; mask <<= 1) {
        float om = __shfl_xor(m, mask, 64);
        float oS = __shfl_xor(S, mask, 64);
        int   ok = __shfl_xor(bk_, mask, 64);
        float mm = fmaxf(m, om);
        S = S * expf(m - mm) + oS * expf(om - mm);
        if (om > m || (om == m && ok < bk_)) bk_ = ok;
        m = mm;
      }
      if (tx == 0) {
        int r = ty + 16*i;
        float gm = m_s[r], gS = S_s[r]; int gk = k_s[r];
        float mm = fmaxf(gm, m);
        S_s[r] = gS * expf(gm - mm) + S * expf(m - mm);
        if (m > gm || (m == gm && bk_ < gk)) k_s[r] = bk_;
        m_s[r] = mm;
      }
    }
  }
  __syncthreads();
  if (t < BM) {
    row_m[r0 + t] = m_s[t];
    row_S[r0 + t] = S_s[t];
    row_idx[r0 + t] = k_s[t];
  }
}

// Pass 2: recompute logits, accumulate avg_probs and sample entropy
__global__ __launch_bounds__(256, 2) void k4_pass2(const float* __restrict__ zn,
    const float* __restrict__ wn, const float* __restrict__ w2,
    const float* __restrict__ row_m, const float* __restrict__ row_S,
    float* __restrict__ avg_probs, float* __restrict__ scal) {
  __shared__ __align__(16) float A[BM*LSTR];
  __shared__ __align__(16) float Bt[BN*LSTR];
  __shared__ float w2s[BN];
  __shared__ float colsum[16][BN];
  __shared__ float st_m[BM], st_invS[BM], st_mls[BM];
  __shared__ float red[256];
  int t = threadIdx.x;
  int tx = t & 15, ty = t >> 4;
  int r0 = blockIdx.x * BM;
  if (t < BM) {
    float m = row_m[r0 + t], S = row_S[r0 + t];
    st_m[t] = m; st_invS[t] = 1.f / S; st_mls[t] = m + logf(S);
  }
  float ent_acc = 0.f;
  for (int kb = 0; kb < NCODES; kb += BN) {
    __syncthreads();
    if (t < BN) w2s[t] = w2[kb + t];
    float acc[8][8];
    #pragma unroll
    for (int i = 0; i < 8; ++i)
      #pragma unroll
      for (int j = 0; j < 8; ++j) acc[i][j] = 0.f;
    for (int dc = 0; dc < DIMS; dc += BK) {
      __syncthreads();
      #pragma unroll
      for (int s = 0; s < 4; ++s) {
        int p = t + s*256; int r = p >> 3, q = p & 7;
        *reinterpret_cast<float4*>(&A[r*LSTR + q*4]) =
          *reinterpret_cast<const float4*>(zn + (size_t)(r0 + r)*256 + dc + q*4);
      }
      #pragma unroll
      for (int s = 0; s < 4; ++s) {
        int p = t + s*256; int r = p >> 3, q = p & 7;
        *reinterpret_cast<float4*>(&Bt[r*LSTR + q*4]) =
          *reinterpret_cast<const float4*>(wn + (size_t)(kb + r)*256 + dc + q*4);
      }
      __syncthreads();
      #pragma unroll
      for (int d = 0; d < BK; d += 4) {
        float4 a4[8];
        #pragma unroll
        for (int i = 0; i < 8; ++i)
          a4[i] = *reinterpret_cast<const float4*>(&A[(ty + 16*i)*LSTR + d]);
        #pragma unroll
        for (int j = 0; j < 8; ++j) {
          float4 b4 = *reinterpret_cast<const float4*>(&Bt[(tx + 16*j)*LSTR + d]);
          #pragma unroll
          for (int i = 0; i < 8; ++i)
            acc[i][j] += a4[i].x*b4.x + a4[i].y*b4.y + a4[i].z*b4.z + a4[i].w*b4.w;
        }
      }
    }
    float ps[8];
    #pragma unroll
    for (int j = 0; j < 8; ++j) ps[j] = 0.f;
    #pragma unroll
    for (int i = 0; i < 8; ++i) {
      int r = ty + 16*i;
      float m = st_m[r], invS = st_invS[r], mls = st_mls[r];
      #pragma unroll
      for (int j = 0; j < 8; ++j) {
        int k = tx + 16*j;
        float l = 200.f*acc[i][j] - 100.f*w2s[k];
        float p = expf(l - m) * invS;
        ent_acc -= p * (l - mls);
        ps[j] += p;
      }
    }
    __syncthreads();
    #pragma unroll
    for (int j = 0; j < 8; ++j) colsum[ty][tx + 16*j] = ps[j];
    __syncthreads();
    if (t < BN) {
      float s = 0.f;
      #pragma unroll
      for (int yy = 0; yy < 16; ++yy) s += colsum[yy][t];
      atomicAdd(&avg_probs[kb + t], s * (1.f/16384.f));
    }
  }
  __syncthreads();
  red[t] = ent_acc;
  __syncthreads();
  for (int s = 128; s; s >>= 1) { if (t < s) red[t] += red[t+s]; __syncthreads(); }
  if (t == 0) atomicAdd(&scal[1], red[0]);
}

// gather q = wn[idx], codebook loss, write z_q channel-first
__global__ __launch_bounds__(256) void k5_gather(const float* __restrict__ zn,
    const float* __restrict__ wn, const int* __restrict__ row_idx,
    float* __restrict__ out_zq, float* __restrict__ scal) {
  __shared__ float tile[256][33];
  __shared__ float red4[4];
  __shared__ float red[256];
  int bh = blockIdx.x, t = threadIdx.x;
  int b = bh >> 5, h = bh & 31;
  float cb = 0.f;
  for (int w = 0; w < 32; ++w) {
    int r = bh*32 + w;
    int idx = row_idx[r];
    float q = wn[(size_t)idx*256 + t];
    float s = q*q;
    #pragma unroll
    for (int mask = 32; mask; mask >>= 1) s += __shfl_xor(s, mask, 64);
    if ((t & 63) == 0) red4[t >> 6] = s;
    __syncthreads();
    float tot = red4[0] + red4[1] + red4[2] + red4[3];
    float inv = 1.f / fmaxf(sqrtf(tot), 1e-6f);
    float zv = zn[(size_t)r*256 + t];
    float d = q*inv - zv;
    cb += d*d;
    tile[t][w] = q;
    __syncthreads();
  }
  red[t] = cb;
  __syncthreads();
  for (int s2 = 128; s2; s2 >>= 1) { if (t < s2) red[t] += red[t+s2]; __syncthreads(); }
  if (t == 0) atomicAdd(&scal[0], red[0]);
  float* ob = out_zq + (size_t)b*256*1024 + (size_t)h*32;
  for (int j = 0; j < 32; ++j) {
    int i = t + j*256; int c = i >> 5, ww = i & 31;
    ob[(size_t)c*1024 + ww] = tile[c][ww];
  }
}

// finalize scalars + emit indices as float
__global__ __launch_bounds__(256) void k6_final(const float* __restrict__ avg_probs,
    const float* __restrict__ scal, const int* __restrict__ row_idx,
    float* __restrict__ out) {
  int t = threadIdx.x;
  if (blockIdx.x < 64) {
    int r = blockIdx.x*256 + t;
    out[4194307 + r] = (float)row_idx[r];
    return;
  }
  __shared__ float red[256];
  float s = 0.f;
  for (int j = 0; j < 32; ++j) {
    float v = avg_probs[t + j*256];
    s -= v * logf(v + 1e-5f);
  }
  red[t] = s;
  __syncthreads();
  for (int q = 128; q; q >>= 1) { if (t < q) red[t] += red[t+q]; __syncthreads(); }
  if (t == 0) {
    float avg_entropy = red[0];
    float sample_entropy = scal[1] * (1.f/16384.f);
    float cb = scal[0] * (1.f/4194304.f);
    out[4194304] = cb;
    out[4194305] = 0.25f * cb;
    out[4194306] = 0.1f * (sample_entropy - avg_entropy);
  }
}

extern "C" void kernel_launch(void* const* d_in, const int* in_sizes, int n_in,
                              void* d_out, int out_size, void* d_ws, size_t ws_size,
                              hipStream_t stream) {
  const float* z   = (const float*)d_in[0];
  const float* emb = (const float*)d_in[1];
  const float* pw  = (const float*)d_in[2];
  const float* pb  = (const float*)d_in[3];
  float* ws  = (float*)d_ws;
  float* out = (float*)d_out;
  float* wn   = ws + OFF_WN;
  float* w2   = ws + OFF_W2;
  float* zn   = ws + OFF_ZN;
  float* rm   = ws + OFF_RM;
  float* rS   = ws + OFF_RS;
  int*   ridx = (int*)(ws + OFF_RIDX);
  float* avgp = ws + OFF_AVGP;
  float* scal = ws + OFF_SCAL;

  k0_init<<<32, 256, 0, stream>>>(ws);
  k1_codebook<<<NCODES, 256, 0, stream>>>(emb, pw, pb, wn, w2);
  k2_zn<<<512, 256, 0, stream>>>(z, zn);
  k3_pass1<<<NROWS/BM, 256, 0, stream>>>(zn, wn, w2, rm, rS, ridx);
  k4_pass2<<<NROWS/BM, 256, 0, stream>>>(zn, wn, w2, rm, rS, avgp, scal);
  k5_gather<<<512, 256, 0, stream>>>(zn, wn, ridx, out, scal);
  k6_final<<<65, 256, 0, stream>>>(avgp, scal, ridx, out);
}

// Round 4
// 1592.686 us; speedup vs baseline: 39.5546x; 28.5449x over previous
//
#include <hip/hip_runtime.h>
#include <math.h>

// Problem constants
#define NROWS 16384      // B*H*W = 16*32*32
#define NCODES 8192
#define DIMS 256

// ws layout (float offsets)
#define OFF_WN   0u          // fp32 wn       8192*256
#define OFF_W2   2097152u    // fp32 w2       8192
#define OFF_ZN   2105344u    // fp32 zn       16384*256
#define OFF_WNH  6299648u    // ushort wn_hi  8192*256   (1,048,576 floats)
#define OFF_WNL  7348224u    // ushort wn_lo
#define OFF_ZNH  8396800u    // ushort zn_hi  16384*256  (2,097,152 floats)
#define OFF_ZNL  10493952u   // ushort zn_lo
#define OFF_PL1  12591104u   // [2][16384] partial top1 logit
#define OFF_PL2  12623872u   // [2][16384] partial top2 logit
#define OFF_PS   12656640u   // [2][16384] partial sum-exp
#define OFF_PI1  12689408u   // [2][16384] partial top1 idx (int)
#define OFF_PI2  12722176u   // [2][16384] partial top2 idx (int)
#define OFF_RM   12754944u   // 16384 final row max-logit
#define OFF_RS   12771328u   // 16384 final row sum-exp
#define OFF_RIDX 12787712u   // 16384 final exact argmin (int)
#define OFF_AVGP 12804096u   // 8192 avg_probs
#define OFF_SCAL 12812288u   // [0]=cb_sum [1]=ent_sum
// total 12,812,304 floats = 48.9 MiB

typedef __attribute__((ext_vector_type(8))) short bf16x8;
typedef __attribute__((ext_vector_type(4))) float f32x4;
typedef unsigned short u16;

#define LROW 40   // ushort stride per LDS tile row (32 dims + 8 pad = 80B; 16B-aligned, bank-spread)

__device__ __forceinline__ u16 f2bf(float f) {          // RNE float->bf16 (finite inputs)
  unsigned u = __float_as_uint(f);
  u += 0x7fffu + ((u >> 16) & 1u);
  return (u16)(u >> 16);
}
__device__ __forceinline__ float bf2f(u16 s) { return __uint_as_float(((unsigned)s) << 16); }

// top-2 insert ordered by (value desc, index asc)
__device__ __forceinline__ void ins2(float x, int idx, float& b1, int& i1, float& b2, int& i2) {
  if (x > b1 || (x == b1 && idx < i1)) { b2 = b1; i2 = i1; b1 = x; i1 = idx; }
  else if (x > b2 || (x == b2 && idx < i2)) { b2 = x; i2 = idx; }
}

__global__ __launch_bounds__(256) void k0_init(float* ws) {
  int i = blockIdx.x * 256 + threadIdx.x;
  if (i < NCODES) ws[OFF_AVGP + i] = 0.f;
  if (i < 16) ws[OFF_SCAL + i] = 0.f;
}

// weight = emb @ proj_w^T + b ; wn = normalize(weight); w2 = sum(wn^2); + bf16 hi/lo planes
__global__ __launch_bounds__(256) void k1_codebook(const float* __restrict__ emb,
    const float* __restrict__ pw, const float* __restrict__ pb,
    float* __restrict__ wn, float* __restrict__ w2,
    u16* __restrict__ wnh, u16* __restrict__ wnl) {
  __shared__ float e[256];
  __shared__ float red[256];
  int k = blockIdx.x, t = threadIdx.x;
  e[t] = emb[(size_t)k * 256 + t];
  __syncthreads();
  const float4* prow = reinterpret_cast<const float4*>(pw + (size_t)t * 256);
  float acc = pb[t];
  #pragma unroll 8
  for (int q = 0; q < 64; ++q) {
    float4 p4 = prow[q];
    acc += e[q*4+0]*p4.x + e[q*4+1]*p4.y + e[q*4+2]*p4.z + e[q*4+3]*p4.w;
  }
  red[t] = acc * acc;
  __syncthreads();
  for (int s = 128; s; s >>= 1) { if (t < s) red[t] += red[t+s]; __syncthreads(); }
  float inv = 1.f / fmaxf(sqrtf(red[0]), 1e-6f);
  float v = acc * inv;
  size_t o = (size_t)k*256 + t;
  wn[o] = v;
  u16 hb = f2bf(v); float hf = bf2f(hb);
  wnh[o] = hb; wnl[o] = f2bf(v - hf);
  __syncthreads();
  red[t] = v * v;
  __syncthreads();
  for (int s = 128; s; s >>= 1) { if (t < s) red[t] += red[t+s]; __syncthreads(); }
  if (t == 0) w2[k] = red[0];
}

// zn = normalize over channel dim; z is [B,C,H,W]; zn row-major [row][C] + bf16 hi/lo
__global__ __launch_bounds__(256) void k2_zn(const float* __restrict__ z,
    float* __restrict__ zn, u16* __restrict__ znh, u16* __restrict__ znl) {
  __shared__ float tile[256][33];
  __shared__ float inv[32];
  int bh = blockIdx.x, t = threadIdx.x;
  const float* zb = z + (size_t)(bh >> 5) * (256*1024) + (size_t)(bh & 31) * 32;
  for (int j = 0; j < 32; ++j) {
    int i = t + j*256; int c = i >> 5, w = i & 31;
    tile[c][w] = zb[(size_t)c*1024 + w];
  }
  __syncthreads();
  if (t < 32) {
    float s = 0.f;
    for (int c = 0; c < 256; ++c) { float v = tile[c][t]; s += v*v; }
    inv[t] = 1.f / fmaxf(sqrtf(s), 1e-6f);
  }
  __syncthreads();
  size_t base = (size_t)bh * 32 * 256;
  for (int w = 0; w < 32; ++w) {
    float v = tile[t][w] * inv[w];
    size_t o = base + (size_t)w*256 + t;
    zn[o] = v;
    u16 hb = f2bf(v); float hf = bf2f(hb);
    znh[o] = hb; znl[o] = f2bf(v - hf);
  }
}

// ---- Pass 1 (MFMA): per-row online (max logit, sum exp, approx top-2). ----
// logit = 200*dot - 100*w2[k] (row-constant -100*z2 dropped; softmax/argmin shift-invariant)
// Split-bf16: dot ~= ah*bh + ah*bl + al*bh (drop ll). Swapped operands: A=codes(M), B=rows(N).
// C/D layout (m89): code = (lane>>4)*4+reg (+16*i +64*wxc), row = lane&15 (+16*jr +32*wy).
// Grid 512 = 256 row-blocks x 2 code-halves. amdgpu_waves_per_eu(2,2): firm 256-VGPR budget
// (launch_bounds min-floor alone let the allocator target higher occupancy and spill; R2/R3).
__global__ __attribute__((amdgpu_flat_work_group_size(256,256)))
__attribute__((amdgpu_waves_per_eu(2,2))) void k3_pass1(
    const u16* __restrict__ znh, const u16* __restrict__ znl,
    const u16* __restrict__ wnh, const u16* __restrict__ wnl,
    const float* __restrict__ w2,
    float* __restrict__ pL1, float* __restrict__ pL2, float* __restrict__ pS,
    int* __restrict__ pI1, int* __restrict__ pI2) {
  __shared__ u16 Ch[128*LROW], Cl[128*LROW];   // code tile (128 codes x 32 dims)
  __shared__ u16 Rh[64*LROW],  Rl[64*LROW];    // row tile  (64 rows x 32 dims)
  __shared__ float w2s[128];
  __shared__ float mrgF[2][2][32][3];
  __shared__ int   mrgI[2][2][32][2];
  int t = threadIdx.x;
  int rb = blockIdx.x & 255, cs = blockIdx.x >> 8;
  int r0 = rb * 64;
  int w = t >> 6, l = t & 63;
  int wxc = w & 1, wy = w >> 1;
  int g = l >> 4, lr = l & 15;
  int koff = g * 8;
  float rL1[2] = {-3.0e38f, -3.0e38f}, rL2[2] = {-3.0e38f, -3.0e38f}, rSv[2] = {0.f, 0.f};
  int rI1[2] = {0x7fffffff, 0x7fffffff}, rI2[2] = {0x7fffffff, 0x7fffffff};

  for (int kt = 0; kt < 32; ++kt) {
    int kb = cs * 4096 + kt * 128;
    __syncthreads();
    if (t < 128) w2s[t] = w2[kb + t];
    f32x4 acc[4][2];
    #pragma unroll
    for (int i = 0; i < 4; ++i) { acc[i][0] = (f32x4){0.f,0.f,0.f,0.f}; acc[i][1] = (f32x4){0.f,0.f,0.f,0.f}; }
    for (int dc = 0; dc < 256; dc += 32) {
      __syncthreads();
      {
        int row = t >> 2, q = t & 3;
        size_t go = (size_t)(kb + row) * 256 + dc + q * 8;
        *(float4*)&Ch[row*LROW + q*8] = *(const float4*)&wnh[go];
        *(float4*)&Cl[row*LROW + q*8] = *(const float4*)&wnl[go];
        int c2 = t + 256, row2 = c2 >> 2, q2 = c2 & 3;
        size_t go2 = (size_t)(kb + row2) * 256 + dc + q2 * 8;
        *(float4*)&Ch[row2*LROW + q2*8] = *(const float4*)&wnh[go2];
        *(float4*)&Cl[row2*LROW + q2*8] = *(const float4*)&wnl[go2];
        size_t go3 = (size_t)(r0 + row) * 256 + dc + q * 8;
        *(float4*)&Rh[row*LROW + q*8] = *(const float4*)&znh[go3];
        *(float4*)&Rl[row*LROW + q*8] = *(const float4*)&znl[go3];
      }
      __syncthreads();
      bf16x8 bh0 = *(const bf16x8*)&Rh[(wy*32 + lr)*LROW + koff];
      bf16x8 bl0 = *(const bf16x8*)&Rl[(wy*32 + lr)*LROW + koff];
      bf16x8 bh1 = *(const bf16x8*)&Rh[(wy*32 + 16 + lr)*LROW + koff];
      bf16x8 bl1 = *(const bf16x8*)&Rl[(wy*32 + 16 + lr)*LROW + koff];
      #pragma unroll
      for (int i = 0; i < 4; ++i) {
        int co = (wxc*64 + i*16 + lr)*LROW + koff;
        bf16x8 ah = *(const bf16x8*)&Ch[co];
        bf16x8 al = *(const bf16x8*)&Cl[co];
        acc[i][0] = __builtin_amdgcn_mfma_f32_16x16x32_bf16(ah, bh0, acc[i][0], 0, 0, 0);
        acc[i][1] = __builtin_amdgcn_mfma_f32_16x16x32_bf16(ah, bh1, acc[i][1], 0, 0, 0);
        acc[i][0] = __builtin_amdgcn_mfma_f32_16x16x32_bf16(ah, bl0, acc[i][0], 0, 0, 0);
        acc[i][1] = __builtin_amdgcn_mfma_f32_16x16x32_bf16(ah, bl1, acc[i][1], 0, 0, 0);
        acc[i][0] = __builtin_amdgcn_mfma_f32_16x16x32_bf16(al, bh0, acc[i][0], 0, 0, 0);
        acc[i][1] = __builtin_amdgcn_mfma_f32_16x16x32_bf16(al, bh1, acc[i][1], 0, 0, 0);
      }
    }
    float wv[16];
    #pragma unroll
    for (int n = 0; n < 16; ++n) wv[n] = w2s[wxc*64 + (n>>2)*16 + g*4 + (n&3)];
    #pragma unroll
    for (int jr = 0; jr < 2; ++jr) {
      float b1 = -3.0e38f, b2 = -3.0e38f; int i1 = 0x7fffffff, i2 = 0x7fffffff;
      #pragma unroll
      for (int i = 0; i < 4; ++i)
        #pragma unroll
        for (int v = 0; v < 4; ++v) {
          float x = 200.f*acc[i][jr][v] - 100.f*wv[i*4+v];
          ins2(x, kb + wxc*64 + i*16 + g*4 + v, b1, i1, b2, i2);
        }
      float S = 0.f;
      #pragma unroll
      for (int i = 0; i < 4; ++i)
        #pragma unroll
        for (int v = 0; v < 4; ++v) {
          float x = 200.f*acc[i][jr][v] - 100.f*wv[i*4+v];
          S += __expf(x - b1);
        }
      // lanes l^16, l^32 share this row (same lr), hold other codes: butterfly merge
      #pragma unroll
      for (int mask = 16; mask <= 32; mask <<= 1) {
        float ob1 = __shfl_xor(b1, mask, 64);
        float ob2 = __shfl_xor(b2, mask, 64);
        float oS  = __shfl_xor(S,  mask, 64);
        int   oi1 = __shfl_xor(i1, mask, 64);
        int   oi2 = __shfl_xor(i2, mask, 64);
        float pb1 = b1;
        ins2(ob1, oi1, b1, i1, b2, i2);
        ins2(ob2, oi2, b1, i1, b2, i2);
        S = S * __expf(pb1 - b1) + oS * __expf(ob1 - b1);
      }
      float pr = rL1[jr];
      ins2(b1, i1, rL1[jr], rI1[jr], rL2[jr], rI2[jr]);
      ins2(b2, i2, rL1[jr], rI1[jr], rL2[jr], rI2[jr]);
      rSv[jr] = rSv[jr] * __expf(pr - rL1[jr]) + S * __expf(b1 - rL1[jr]);
    }
  }
  // merge the two code-half waves (same rows) via LDS, write per-(cs) partials
  __syncthreads();
  if (g == 0) {
    #pragma unroll
    for (int jr = 0; jr < 2; ++jr) {
      int ri = jr*16 + lr;
      mrgF[wy][wxc][ri][0] = rL1[jr]; mrgF[wy][wxc][ri][1] = rL2[jr]; mrgF[wy][wxc][ri][2] = rSv[jr];
      mrgI[wy][wxc][ri][0] = rI1[jr]; mrgI[wy][wxc][ri][1] = rI2[jr];
    }
  }
  __syncthreads();
  if (t < 64) {
    int wyy = t >> 5, ri = t & 31;
    float b1 = mrgF[wyy][0][ri][0], b2 = mrgF[wyy][0][ri][1], S = mrgF[wyy][0][ri][2];
    int i1 = mrgI[wyy][0][ri][0], i2 = mrgI[wyy][0][ri][1];
    float ob1 = mrgF[wyy][1][ri][0], ob2 = mrgF[wyy][1][ri][1], oS = mrgF[wyy][1][ri][2];
    int oi1 = mrgI[wyy][1][ri][0], oi2 = mrgI[wyy][1][ri][1];
    float pb1 = b1;
    ins2(ob1, oi1, b1, i1, b2, i2);
    ins2(ob2, oi2, b1, i1, b2, i2);
    S = S * __expf(pb1 - b1) + oS * __expf(ob1 - b1);
    int r = r0 + wyy*32 + ri;
    size_t o = (size_t)cs * NROWS + r;
    pL1[o] = b1; pL2[o] = b2; pS[o] = S;
    pI1[o] = i1; pI2[o] = i2;
  }
}

// merge code-half partials; exact fp32 re-score of top-2 -> final argmin, row max, sum
__global__ __launch_bounds__(256) void k3b_refine(
    const float* __restrict__ zn, const float* __restrict__ wn, const float* __restrict__ w2,
    const float* __restrict__ pL1, const float* __restrict__ pL2, const float* __restrict__ pS,
    const int* __restrict__ pI1, const int* __restrict__ pI2,
    float* __restrict__ rm, float* __restrict__ rs, int* __restrict__ ridx) {
  int t = threadIdx.x;
  int r = blockIdx.x * 4 + (t >> 6);
  int l = t & 63;
  float b1 = pL1[r], b2 = pL2[r], S = pS[r];
  int i1 = pI1[r], i2 = pI2[r];
  float ob1 = pL1[NROWS + r], ob2 = pL2[NROWS + r], oS = pS[NROWS + r];
  int oi1 = pI1[NROWS + r], oi2 = pI2[NROWS + r];
  float pb1 = b1;
  ins2(ob1, oi1, b1, i1, b2, i2);
  ins2(ob2, oi2, b1, i1, b2, i2);
  S = S * __expf(pb1 - b1) + oS * __expf(ob1 - b1);
  int cand = (l < 32) ? i1 : i2;
  int lo = l & 31;
  const float* zr = zn + (size_t)r * 256;
  const float* wc = wn + (size_t)cand * 256;
  float d = 0.f;
  #pragma unroll
  for (int q = 0; q < 8; ++q) d += zr[lo + q*32] * wc[lo + q*32];
  #pragma unroll
  for (int mask = 1; mask <= 16; mask <<= 1) d += __shfl_xor(d, mask, 64);
  float dOther = __shfl_xor(d, 32, 64);
  if (l == 0) {
    float s1 = w2[i1] - 2.f*d;       // z2 common term dropped
    float s2 = w2[i2] - 2.f*dOther;
    int win = i1;
    if (s2 < s1 || (s2 == s1 && i2 < i1)) win = i2;
    rm[r] = b1; rs[r] = S; ridx[r] = win;
  }
}

// ---- Pass 2 (MFMA): recompute logits; avg_probs + sample entropy ----
__global__ __attribute__((amdgpu_flat_work_group_size(256,256)))
__attribute__((amdgpu_waves_per_eu(2,2))) void k4_pass2(
    const u16* __restrict__ znh, const u16* __restrict__ znl,
    const u16* __restrict__ wnh, const u16* __restrict__ wnl,
    const float* __restrict__ w2,
    const float* __restrict__ rm, const float* __restrict__ rs,
    float* __restrict__ avgp, float* __restrict__ scal) {
  __shared__ u16 Ch[128*LROW], Cl[128*LROW];
  __shared__ u16 Rh[64*LROW],  Rl[64*LROW];
  __shared__ float w2s[128];
  __shared__ float avgLds[2][128];
  __shared__ float red[256];
  int t = threadIdx.x;
  int rb = blockIdx.x & 255, cs = blockIdx.x >> 8;
  int r0 = rb * 64;
  int w = t >> 6, l = t & 63;
  int wxc = w & 1, wy = w >> 1;
  int g = l >> 4, lr = l & 15;
  int koff = g * 8;
  float m_[2], invS[2], mls[2];
  #pragma unroll
  for (int jr = 0; jr < 2; ++jr) {
    int r = r0 + wy*32 + jr*16 + lr;
    float mm = rm[r], ss = rs[r];
    m_[jr] = mm; invS[jr] = 1.f / ss; mls[jr] = mm + __logf(ss);
  }
  float ent = 0.f;
  for (int kt = 0; kt < 32; ++kt) {
    int kb = cs * 4096 + kt * 128;
    __syncthreads();
    if (t < 128) w2s[t] = w2[kb + t];
    f32x4 acc[4][2];
    #pragma unroll
    for (int i = 0; i < 4; ++i) { acc[i][0] = (f32x4){0.f,0.f,0.f,0.f}; acc[i][1] = (f32x4){0.f,0.f,0.f,0.f}; }
    for (int dc = 0; dc < 256; dc += 32) {
      __syncthreads();
      {
        int row = t >> 2, q = t & 3;
        size_t go = (size_t)(kb + row) * 256 + dc + q * 8;
        *(float4*)&Ch[row*LROW + q*8] = *(const float4*)&wnh[go];
        *(float4*)&Cl[row*LROW + q*8] = *(const float4*)&wnl[go];
        int c2 = t + 256, row2 = c2 >> 2, q2 = c2 & 3;
        size_t go2 = (size_t)(kb + row2) * 256 + dc + q2 * 8;
        *(float4*)&Ch[row2*LROW + q2*8] = *(const float4*)&wnh[go2];
        *(float4*)&Cl[row2*LROW + q2*8] = *(const float4*)&wnl[go2];
        size_t go3 = (size_t)(r0 + row) * 256 + dc + q * 8;
        *(float4*)&Rh[row*LROW + q*8] = *(const float4*)&znh[go3];
        *(float4*)&Rl[row*LROW + q*8] = *(const float4*)&znl[go3];
      }
      __syncthreads();
      bf16x8 bh0 = *(const bf16x8*)&Rh[(wy*32 + lr)*LROW + koff];
      bf16x8 bl0 = *(const bf16x8*)&Rl[(wy*32 + lr)*LROW + koff];
      bf16x8 bh1 = *(const bf16x8*)&Rh[(wy*32 + 16 + lr)*LROW + koff];
      bf16x8 bl1 = *(const bf16x8*)&Rl[(wy*32 + 16 + lr)*LROW + koff];
      #pragma unroll
      for (int i = 0; i < 4; ++i) {
        int co = (wxc*64 + i*16 + lr)*LROW + koff;
        bf16x8 ah = *(const bf16x8*)&Ch[co];
        bf16x8 al = *(const bf16x8*)&Cl[co];
        acc[i][0] = __builtin_amdgcn_mfma_f32_16x16x32_bf16(ah, bh0, acc[i][0], 0, 0, 0);
        acc[i][1] = __builtin_amdgcn_mfma_f32_16x16x32_bf16(ah, bh1, acc[i][1], 0, 0, 0);
        acc[i][0] = __builtin_amdgcn_mfma_f32_16x16x32_bf16(ah, bl0, acc[i][0], 0, 0, 0);
        acc[i][1] = __builtin_amdgcn_mfma_f32_16x16x32_bf16(ah, bl1, acc[i][1], 0, 0, 0);
        acc[i][0] = __builtin_amdgcn_mfma_f32_16x16x32_bf16(al, bh0, acc[i][0], 0, 0, 0);
        acc[i][1] = __builtin_amdgcn_mfma_f32_16x16x32_bf16(al, bh1, acc[i][1], 0, 0, 0);
      }
    }
    float wv[16];
    #pragma unroll
    for (int n = 0; n < 16; ++n) wv[n] = w2s[wxc*64 + (n>>2)*16 + g*4 + (n&3)];
    float codeAcc[16];
    #pragma unroll
    for (int n = 0; n < 16; ++n) codeAcc[n] = 0.f;
    #pragma unroll
    for (int jr = 0; jr < 2; ++jr)
      #pragma unroll
      for (int i = 0; i < 4; ++i)
        #pragma unroll
        for (int v = 0; v < 4; ++v) {
          float x = 200.f*acc[i][jr][v] - 100.f*wv[i*4+v];
          float p = __expf(x - m_[jr]) * invS[jr];
          ent -= p * (x - mls[jr]);
          codeAcc[i*4+v] += p;
        }
    // lanes sharing (g,n) hold the same code across 16 rows: reduce over lr
    #pragma unroll
    for (int n = 0; n < 16; ++n) {
      float s = codeAcc[n];
      s += __shfl_xor(s, 1, 64);
      s += __shfl_xor(s, 2, 64);
      s += __shfl_xor(s, 4, 64);
      s += __shfl_xor(s, 8, 64);
      if (lr == 0) avgLds[wy][wxc*64 + (n>>2)*16 + g*4 + (n&3)] = s;
    }
    __syncthreads();
    if (t < 128) atomicAdd(&avgp[kb + t], (avgLds[0][t] + avgLds[1][t]) * (1.f/16384.f));
  }
  red[t] = ent;
  __syncthreads();
  for (int s2 = 128; s2; s2 >>= 1) { if (t < s2) red[t] += red[t + s2]; __syncthreads(); }
  if (t == 0) atomicAdd(&scal[1], red[0]);
}

// gather q = wn[idx], codebook loss, write z_q channel-first
__global__ __launch_bounds__(256) void k5_gather(const float* __restrict__ zn,
    const float* __restrict__ wn, const int* __restrict__ row_idx,
    float* __restrict__ out_zq, float* __restrict__ scal) {
  __shared__ float tile[256][33];
  __shared__ float red4[4];
  __shared__ float red[256];
  int bh = blockIdx.x, t = threadIdx.x;
  int b = bh >> 5, h = bh & 31;
  float cb = 0.f;
  for (int w = 0; w < 32; ++w) {
    int r = bh*32 + w;
    int idx = row_idx[r];
    float q = wn[(size_t)idx*256 + t];
    float s = q*q;
    #pragma unroll
    for (int mask = 32; mask; mask >>= 1) s += __shfl_xor(s, mask, 64);
    if ((t & 63) == 0) red4[t >> 6] = s;
    __syncthreads();
    float tot = red4[0] + red4[1] + red4[2] + red4[3];
    float inv = 1.f / fmaxf(sqrtf(tot), 1e-6f);
    float zv = zn[(size_t)r*256 + t];
    float d = q*inv - zv;
    cb += d*d;
    tile[t][w] = q;
    __syncthreads();
  }
  red[t] = cb;
  __syncthreads();
  for (int s2 = 128; s2; s2 >>= 1) { if (t < s2) red[t] += red[t+s2]; __syncthreads(); }
  if (t == 0) atomicAdd(&scal[0], red[0]);
  float* ob = out_zq + (size_t)b*256*1024 + (size_t)h*32;
  for (int j = 0; j < 32; ++j) {
    int i = t + j*256; int c = i >> 5, ww = i & 31;
    ob[(size_t)c*1024 + ww] = tile[c][ww];
  }
}

// finalize scalars + emit indices as float
__global__ __launch_bounds__(256) void k6_final(const float* __restrict__ avg_probs,
    const float* __restrict__ scal, const int* __restrict__ row_idx,
    float* __restrict__ out) {
  int t = threadIdx.x;
  if (blockIdx.x < 64) {
    int r = blockIdx.x*256 + t;
    out[4194307 + r] = (float)row_idx[r];
    return;
  }
  __shared__ float red[256];
  float s = 0.f;
  for (int j = 0; j < 32; ++j) {
    float v = avg_probs[t + j*256];
    s -= v * logf(v + 1e-5f);
  }
  red[t] = s;
  __syncthreads();
  for (int q = 128; q; q >>= 1) { if (t < q) red[t] += red[t+q]; __syncthreads(); }
  if (t == 0) {
    float avg_entropy = red[0];
    float sample_entropy = scal[1] * (1.f/16384.f);
    float cb = scal[0] * (1.f/4194304.f);
    out[4194304] = cb;
    out[4194305] = 0.25f * cb;
    out[4194306] = 0.1f * (sample_entropy - avg_entropy);
  }
}

extern "C" void kernel_launch(void* const* d_in, const int* in_sizes, int n_in,
                              void* d_out, int out_size, void* d_ws, size_t ws_size,
                              hipStream_t stream) {
  const float* z   = (const float*)d_in[0];
  const float* emb = (const float*)d_in[1];
  const float* pw  = (const float*)d_in[2];
  const float* pb  = (const float*)d_in[3];
  float* ws  = (float*)d_ws;
  float* out = (float*)d_out;
  float* wn   = ws + OFF_WN;
  float* w2   = ws + OFF_W2;
  float* zn   = ws + OFF_ZN;
  u16*   wnh  = (u16*)(ws + OFF_WNH);
  u16*   wnl  = (u16*)(ws + OFF_WNL);
  u16*   znh  = (u16*)(ws + OFF_ZNH);
  u16*   znl  = (u16*)(ws + OFF_ZNL);
  float* pL1  = ws + OFF_PL1;
  float* pL2  = ws + OFF_PL2;
  float* pS   = ws + OFF_PS;
  int*   pI1  = (int*)(ws + OFF_PI1);
  int*   pI2  = (int*)(ws + OFF_PI2);
  float* rm   = ws + OFF_RM;
  float* rs   = ws + OFF_RS;
  int*   ridx = (int*)(ws + OFF_RIDX);
  float* avgp = ws + OFF_AVGP;
  float* scal = ws + OFF_SCAL;

  k0_init<<<32, 256, 0, stream>>>(ws);
  k1_codebook<<<NCODES, 256, 0, stream>>>(emb, pw, pb, wn, w2, wnh, wnl);
  k2_zn<<<512, 256, 0, stream>>>(z, zn, znh, znl);
  k3_pass1<<<512, 256, 0, stream>>>(znh, znl, wnh, wnl, w2, pL1, pL2, pS, pI1, pI2);
  k3b_refine<<<NROWS/4, 256, 0, stream>>>(zn, wn, w2, pL1, pL2, pS, pI1, pI2, rm, rs, ridx);
  k4_pass2<<<512, 256, 0, stream>>>(znh, znl, wnh, wnl, w2, rm, rs, avgp, scal);
  k5_gather<<<512, 256, 0, stream>>>(zn, wn, ridx, out, scal);
  k6_final<<<65, 256, 0, stream>>>(avgp, scal, ridx, out);
}

// Round 6
// 1398.457 us; speedup vs baseline: 45.0483x; 1.1389x over previous
//
#include <hip/hip_runtime.h>
#include <math.h>

// Problem constants
#define NROWS 16384      // B*H*W = 16*32*32
#define NCODES 8192
#define DIMS 256

// ws layout (float offsets)
#define OFF_WN   0u          // fp32 wn       8192*256
#define OFF_W2   2097152u    // fp32 w2       8192
#define OFF_ZN   2105344u    // fp32 zn       16384*256
#define OFF_WNH  6299648u    // ushort wn_hi  8192*256   (1,048,576 floats)
#define OFF_WNL  7348224u    // ushort wn_lo
#define OFF_ZNH  8396800u    // ushort zn_hi  16384*256  (2,097,152 floats)
#define OFF_ZNL  10493952u   // ushort zn_lo
#define OFF_PL1  12591104u   // [2][16384] partial top1 logit
#define OFF_PL2  12623872u   // [2][16384] partial top2 logit
#define OFF_PS   12656640u   // [2][16384] partial sum-exp
#define OFF_PI1  12689408u   // [2][16384] partial top1 idx (int)
#define OFF_PI2  12722176u   // [2][16384] partial top2 idx (int)
#define OFF_RM   12754944u   // 16384 final row max-logit
#define OFF_RS   12771328u   // 16384 final row sum-exp
#define OFF_RIDX 12787712u   // 16384 final exact argmin (int)
#define OFF_AVGP 12804096u   // 8192 avg_probs
#define OFF_SCAL 12812288u   // [0]=cb_sum [1]=ent_sum

typedef __attribute__((ext_vector_type(8))) short bf16x8;
typedef __attribute__((ext_vector_type(4))) float f32x4;
typedef unsigned short u16;

__device__ __forceinline__ u16 f2bf(float f) {          // RNE float->bf16 (finite inputs)
  unsigned u = __float_as_uint(f);
  u += 0x7fffu + ((u >> 16) & 1u);
  return (u16)(u >> 16);
}
__device__ __forceinline__ float bf2f(u16 s) { return __uint_as_float(((unsigned)s) << 16); }

// async global->LDS, 16B per lane; LDS dest is wave-uniform base + lane*16
__device__ __forceinline__ void gl_lds16(const u16* g, u16* l) {
  __builtin_amdgcn_global_load_lds(
      (const __attribute__((address_space(1))) unsigned*)g,
      (__attribute__((address_space(3))) unsigned*)l, 16, 0, 0);
}

// top-2 insert ordered by (value desc, index asc)
__device__ __forceinline__ void ins2(float x, int idx, float& b1, int& i1, float& b2, int& i2) {
  if (x > b1 || (x == b1 && idx < i1)) { b2 = b1; i2 = i1; b1 = x; i1 = idx; }
  else if (x > b2 || (x == b2 && idx < i2)) { b2 = x; i2 = idx; }
}

__global__ __launch_bounds__(256) void k0_init(float* ws) {
  int i = blockIdx.x * 256 + threadIdx.x;
  if (i < NCODES) ws[OFF_AVGP + i] = 0.f;
  if (i < 16) ws[OFF_SCAL + i] = 0.f;
}

// weight = emb @ proj_w^T + b ; wn = normalize(weight); w2 = sum(wn^2); + bf16 hi/lo planes
__global__ __launch_bounds__(256) void k1_codebook(const float* __restrict__ emb,
    const float* __restrict__ pw, const float* __restrict__ pb,
    float* __restrict__ wn, float* __restrict__ w2,
    u16* __restrict__ wnh, u16* __restrict__ wnl) {
  __shared__ float e[256];
  __shared__ float red[256];
  int k = blockIdx.x, t = threadIdx.x;
  e[t] = emb[(size_t)k * 256 + t];
  __syncthreads();
  const float4* prow = reinterpret_cast<const float4*>(pw + (size_t)t * 256);
  float acc = pb[t];
  #pragma unroll 8
  for (int q = 0; q < 64; ++q) {
    float4 p4 = prow[q];
    acc += e[q*4+0]*p4.x + e[q*4+1]*p4.y + e[q*4+2]*p4.z + e[q*4+3]*p4.w;
  }
  red[t] = acc * acc;
  __syncthreads();
  for (int s = 128; s; s >>= 1) { if (t < s) red[t] += red[t+s]; __syncthreads(); }
  float inv = 1.f / fmaxf(sqrtf(red[0]), 1e-6f);
  float v = acc * inv;
  size_t o = (size_t)k*256 + t;
  wn[o] = v;
  u16 hb = f2bf(v); float hf = bf2f(hb);
  wnh[o] = hb; wnl[o] = f2bf(v - hf);
  __syncthreads();
  red[t] = v * v;
  __syncthreads();
  for (int s = 128; s; s >>= 1) { if (t < s) red[t] += red[t+s]; __syncthreads(); }
  if (t == 0) w2[k] = red[0];
}

// zn = normalize over channel dim; z is [B,C,H,W]; zn row-major [row][C] + bf16 hi/lo
__global__ __launch_bounds__(256) void k2_zn(const float* __restrict__ z,
    float* __restrict__ zn, u16* __restrict__ znh, u16* __restrict__ znl) {
  __shared__ float tile[256][33];
  __shared__ float inv[32];
  int bh = blockIdx.x, t = threadIdx.x;
  const float* zb = z + (size_t)(bh >> 5) * (256*1024) + (size_t)(bh & 31) * 32;
  for (int j = 0; j < 32; ++j) {
    int i = t + j*256; int c = i >> 5, w = i & 31;
    tile[c][w] = zb[(size_t)c*1024 + w];
  }
  __syncthreads();
  if (t < 32) {
    float s = 0.f;
    for (int c = 0; c < 256; ++c) { float v = tile[c][t]; s += v*v; }
    inv[t] = 1.f / fmaxf(sqrtf(s), 1e-6f);
  }
  __syncthreads();
  size_t base = (size_t)bh * 32 * 256;
  for (int w = 0; w < 32; ++w) {
    float v = tile[t][w] * inv[w];
    size_t o = base + (size_t)w*256 + t;
    zn[o] = v;
    u16 hb = f2bf(v); float hf = bf2f(hb);
    znh[o] = hb; znl[o] = f2bf(v - hf);
  }
}

// ---- Pass 1 (MFMA): per-row online (max logit, sum exp, approx top-2). ----
// logit = 200*dot - 100*w2[k]. Split-bf16: hh + hl + lh (drop ll).
// Rows (B-operand) live in REGISTERS for the whole kernel (32x bf16x8 = 128 VGPR);
// codes staged via global_load_lds (16B) into double-buffered linear LDS [128][64B],
// single barrier per step: prefetch s+1 issued right after the barrier that
// publishes s, so the vmcnt(0)-before-barrier drain lands after a compute phase.
__global__ __attribute__((amdgpu_flat_work_group_size(256,256)))
__attribute__((amdgpu_waves_per_eu(2,2))) void k3_pass1(
    const u16* __restrict__ znh, const u16* __restrict__ znl,
    const u16* __restrict__ wnh, const u16* __restrict__ wnl,
    const float* __restrict__ w2,
    float* __restrict__ pL1, float* __restrict__ pL2, float* __restrict__ pS,
    int* __restrict__ pI1, int* __restrict__ pI2) {
  __shared__ u16 Cbuf[2][2][128*32];    // [dbuf][hi/lo][code*32]  32 KiB
  __shared__ float w2all[4096];         // 16 KiB
  __shared__ float mrgF[2][2][32][3];
  __shared__ int   mrgI[2][2][32][2];
  int t = threadIdx.x;
  int rb = blockIdx.x & 255, cs = blockIdx.x >> 8;
  int r0 = rb * 64;
  int w = t >> 6, l = t & 63;
  int wxc = w & 1, wy = w >> 1;
  int g = l >> 4, lr = l & 15;

  // B-fragments (rows) -> registers, once
  bf16x8 bh[2][8], bl[2][8];
  #pragma unroll
  for (int jr = 0; jr < 2; ++jr) {
    size_t rbase = (size_t)(r0 + wy*32 + jr*16 + lr) * 256;
    #pragma unroll
    for (int dc = 0; dc < 8; ++dc) {
      bh[jr][dc] = *(const bf16x8*)&znh[rbase + dc*32 + g*8];
      bl[jr][dc] = *(const bf16x8*)&znl[rbase + dc*32 + g*8];
    }
  }
  for (int i = t; i < 4096; i += 256) w2all[i] = w2[cs*4096 + i];

  const size_t csbase = (size_t)cs * 4096 * 256;
  auto stage = [&](int s, int b) {
    int dc2 = s & 7;
    int krow = (s >> 3) * 128;
    #pragma unroll
    for (int rnd = 0; rnd < 2; ++rnd) {
      int i = rnd*256 + t;
      int code = i >> 2, q = i & 3;
      size_t go = csbase + (size_t)(krow + code)*256 + dc2*32 + q*8;
      gl_lds16(&wnh[go], &Cbuf[b][0][rnd*2048 + w*512]);
      gl_lds16(&wnl[go], &Cbuf[b][1][rnd*2048 + w*512]);
    }
  };
  stage(0, 0);
  int buf = 0;

  float rL1[2] = {-3.0e38f, -3.0e38f}, rL2[2] = {-3.0e38f, -3.0e38f}, rSv[2] = {0.f, 0.f};
  int rI1[2] = {0x7fffffff, 0x7fffffff}, rI2[2] = {0x7fffffff, 0x7fffffff};

  for (int kt = 0; kt < 32; ++kt) {
    f32x4 acc[4][2];
    #pragma unroll
    for (int i = 0; i < 4; ++i) { acc[i][0] = (f32x4){0.f,0.f,0.f,0.f}; acc[i][1] = (f32x4){0.f,0.f,0.f,0.f}; }
    #pragma unroll
    for (int dc = 0; dc < 8; ++dc) {
      __syncthreads();                       // publishes Cbuf[buf] (drains gload queue)
      int s = kt*8 + dc;
      if (s + 1 < 256) stage(s + 1, buf ^ 1);
      #pragma unroll
      for (int i = 0; i < 4; ++i) {
        int co = (wxc*64 + i*16 + lr)*32 + g*8;
        bf16x8 ah = *(const bf16x8*)&Cbuf[buf][0][co];
        bf16x8 al = *(const bf16x8*)&Cbuf[buf][1][co];
        acc[i][0] = __builtin_amdgcn_mfma_f32_16x16x32_bf16(ah, bh[0][dc], acc[i][0], 0, 0, 0);
        acc[i][1] = __builtin_amdgcn_mfma_f32_16x16x32_bf16(ah, bh[1][dc], acc[i][1], 0, 0, 0);
        acc[i][0] = __builtin_amdgcn_mfma_f32_16x16x32_bf16(ah, bl[0][dc], acc[i][0], 0, 0, 0);
        acc[i][1] = __builtin_amdgcn_mfma_f32_16x16x32_bf16(ah, bl[1][dc], acc[i][1], 0, 0, 0);
        acc[i][0] = __builtin_amdgcn_mfma_f32_16x16x32_bf16(al, bh[0][dc], acc[i][0], 0, 0, 0);
        acc[i][1] = __builtin_amdgcn_mfma_f32_16x16x32_bf16(al, bh[1][dc], acc[i][1], 0, 0, 0);
      }
      buf ^= 1;
    }
    // per-kt stats (regs + w2all only; prefetch for next kt in flight)
    int kb = cs*4096 + kt*128;
    float wv[16];
    #pragma unroll
    for (int n = 0; n < 16; ++n) wv[n] = w2all[kt*128 + wxc*64 + (n>>2)*16 + g*4 + (n&3)];
    #pragma unroll
    for (int jr = 0; jr < 2; ++jr) {
      float b1 = -3.0e38f, b2 = -3.0e38f; int i1 = 0x7fffffff, i2 = 0x7fffffff;
      #pragma unroll
      for (int i = 0; i < 4; ++i)
        #pragma unroll
        for (int v = 0; v < 4; ++v) {
          float x = 200.f*acc[i][jr][v] - 100.f*wv[i*4+v];
          ins2(x, kb + wxc*64 + i*16 + g*4 + v, b1, i1, b2, i2);
        }
      float S = 0.f;
      #pragma unroll
      for (int i = 0; i < 4; ++i)
        #pragma unroll
        for (int v = 0; v < 4; ++v) {
          float x = 200.f*acc[i][jr][v] - 100.f*wv[i*4+v];
          S += __expf(x - b1);
        }
      #pragma unroll
      for (int mask = 16; mask <= 32; mask <<= 1) {
        float ob1 = __shfl_xor(b1, mask, 64);
        float ob2 = __shfl_xor(b2, mask, 64);
        float oS  = __shfl_xor(S,  mask, 64);
        int   oi1 = __shfl_xor(i1, mask, 64);
        int   oi2 = __shfl_xor(i2, mask, 64);
        float pb1 = b1;
        ins2(ob1, oi1, b1, i1, b2, i2);
        ins2(ob2, oi2, b1, i1, b2, i2);
        S = S * __expf(pb1 - b1) + oS * __expf(ob1 - b1);
      }
      float pr = rL1[jr];
      ins2(b1, i1, rL1[jr], rI1[jr], rL2[jr], rI2[jr]);
      ins2(b2, i2, rL1[jr], rI1[jr], rL2[jr], rI2[jr]);
      rSv[jr] = rSv[jr] * __expf(pr - rL1[jr]) + S * __expf(b1 - rL1[jr]);
    }
  }
  // merge the two code-half waves (same rows) via LDS, write per-(cs) partials
  __syncthreads();
  if (g == 0) {
    #pragma unroll
    for (int jr = 0; jr < 2; ++jr) {
      int ri = jr*16 + lr;
      mrgF[wy][wxc][ri][0] = rL1[jr]; mrgF[wy][wxc][ri][1] = rL2[jr]; mrgF[wy][wxc][ri][2] = rSv[jr];
      mrgI[wy][wxc][ri][0] = rI1[jr]; mrgI[wy][wxc][ri][1] = rI2[jr];
    }
  }
  __syncthreads();
  if (t < 64) {
    int wyy = t >> 5, ri = t & 31;
    float b1 = mrgF[wyy][0][ri][0], b2 = mrgF[wyy][0][ri][1], S = mrgF[wyy][0][ri][2];
    int i1 = mrgI[wyy][0][ri][0], i2 = mrgI[wyy][0][ri][1];
    float ob1 = mrgF[wyy][1][ri][0], ob2 = mrgF[wyy][1][ri][1], oS = mrgF[wyy][1][ri][2];
    int oi1 = mrgI[wyy][1][ri][0], oi2 = mrgI[wyy][1][ri][1];
    float pb1 = b1;
    ins2(ob1, oi1, b1, i1, b2, i2);
    ins2(ob2, oi2, b1, i1, b2, i2);
    S = S * __expf(pb1 - b1) + oS * __expf(ob1 - b1);
    int r = r0 + wyy*32 + ri;
    size_t o = (size_t)cs * NROWS + r;
    pL1[o] = b1; pL2[o] = b2; pS[o] = S;
    pI1[o] = i1; pI2[o] = i2;
  }
}

// merge code-half partials; exact fp32 re-score of top-2 -> final argmin, row max, sum
__global__ __launch_bounds__(256) void k3b_refine(
    const float* __restrict__ zn, const float* __restrict__ wn, const float* __restrict__ w2,
    const float* __restrict__ pL1, const float* __restrict__ pL2, const float* __restrict__ pS,
    const int* __restrict__ pI1, const int* __restrict__ pI2,
    float* __restrict__ rm, float* __restrict__ rs, int* __restrict__ ridx) {
  int t = threadIdx.x;
  int r = blockIdx.x * 4 + (t >> 6);
  int l = t & 63;
  float b1 = pL1[r], b2 = pL2[r], S = pS[r];
  int i1 = pI1[r], i2 = pI2[r];
  float ob1 = pL1[NROWS + r], ob2 = pL2[NROWS + r], oS = pS[NROWS + r];
  int oi1 = pI1[NROWS + r], oi2 = pI2[NROWS + r];
  float pb1 = b1;
  ins2(ob1, oi1, b1, i1, b2, i2);
  ins2(ob2, oi2, b1, i1, b2, i2);
  S = S * __expf(pb1 - b1) + oS * __expf(ob1 - b1);
  int cand = (l < 32) ? i1 : i2;
  int lo = l & 31;
  const float* zr = zn + (size_t)r * 256;
  const float* wc = wn + (size_t)cand * 256;
  float d = 0.f;
  #pragma unroll
  for (int q = 0; q < 8; ++q) d += zr[lo + q*32] * wc[lo + q*32];
  #pragma unroll
  for (int mask = 1; mask <= 16; mask <<= 1) d += __shfl_xor(d, mask, 64);
  float dOther = __shfl_xor(d, 32, 64);
  if (l == 0) {
    float s1 = w2[i1] - 2.f*d;       // z2 common term dropped
    float s2 = w2[i2] - 2.f*dOther;
    int win = i1;
    if (s2 < s1 || (s2 == s1 && i2 < i1)) win = i2;
    rm[r] = b1; rs[r] = S; ridx[r] = win;
  }
}

// ---- Pass 2 (MFMA): recompute logits; avg_probs + sample entropy ----
__global__ __attribute__((amdgpu_flat_work_group_size(256,256)))
__attribute__((amdgpu_waves_per_eu(2,2))) void k4_pass2(
    const u16* __restrict__ znh, const u16* __restrict__ znl,
    const u16* __restrict__ wnh, const u16* __restrict__ wnl,
    const float* __restrict__ w2,
    const float* __restrict__ rm, const float* __restrict__ rs,
    float* __restrict__ avgp, float* __restrict__ scal) {
  __shared__ u16 Cbuf[2][2][128*32];
  __shared__ float w2all[4096];
  __shared__ float avgLds[2][128];
  __shared__ float red[256];
  int t = threadIdx.x;
  int rb = blockIdx.x & 255, cs = blockIdx.x >> 8;
  int r0 = rb * 64;
  int w = t >> 6, l = t & 63;
  int wxc = w & 1, wy = w >> 1;
  int g = l >> 4, lr = l & 15;

  bf16x8 bh[2][8], bl[2][8];
  #pragma unroll
  for (int jr = 0; jr < 2; ++jr) {
    size_t rbase = (size_t)(r0 + wy*32 + jr*16 + lr) * 256;
    #pragma unroll
    for (int dc = 0; dc < 8; ++dc) {
      bh[jr][dc] = *(const bf16x8*)&znh[rbase + dc*32 + g*8];
      bl[jr][dc] = *(const bf16x8*)&znl[rbase + dc*32 + g*8];
    }
  }
  for (int i = t; i < 4096; i += 256) w2all[i] = w2[cs*4096 + i];

  float m_[2], invS[2], mls[2];
  #pragma unroll
  for (int jr = 0; jr < 2; ++jr) {
    int r = r0 + wy*32 + jr*16 + lr;
    float mm = rm[r], ss = rs[r];
    m_[jr] = mm; invS[jr] = 1.f / ss; mls[jr] = mm + __logf(ss);
  }

  const size_t csbase = (size_t)cs * 4096 * 256;
  auto stage = [&](int s, int b) {
    int dc2 = s & 7;
    int krow = (s >> 3) * 128;
    #pragma unroll
    for (int rnd = 0; rnd < 2; ++rnd) {
      int i = rnd*256 + t;
      int code = i >> 2, q = i & 3;
      size_t go = csbase + (size_t)(krow + code)*256 + dc2*32 + q*8;
      gl_lds16(&wnh[go], &Cbuf[b][0][rnd*2048 + w*512]);
      gl_lds16(&wnl[go], &Cbuf[b][1][rnd*2048 + w*512]);
    }
  };
  stage(0, 0);
  int buf = 0;
  float ent = 0.f;

  for (int kt = 0; kt < 32; ++kt) {
    f32x4 acc[4][2];
    #pragma unroll
    for (int i = 0; i < 4; ++i) { acc[i][0] = (f32x4){0.f,0.f,0.f,0.f}; acc[i][1] = (f32x4){0.f,0.f,0.f,0.f}; }
    #pragma unroll
    for (int dc = 0; dc < 8; ++dc) {
      __syncthreads();
      int s = kt*8 + dc;
      if (s + 1 < 256) stage(s + 1, buf ^ 1);
      #pragma unroll
      for (int i = 0; i < 4; ++i) {
        int co = (wxc*64 + i*16 + lr)*32 + g*8;
        bf16x8 ah = *(const bf16x8*)&Cbuf[buf][0][co];
        bf16x8 al = *(const bf16x8*)&Cbuf[buf][1][co];
        acc[i][0] = __builtin_amdgcn_mfma_f32_16x16x32_bf16(ah, bh[0][dc], acc[i][0], 0, 0, 0);
        acc[i][1] = __builtin_amdgcn_mfma_f32_16x16x32_bf16(ah, bh[1][dc], acc[i][1], 0, 0, 0);
        acc[i][0] = __builtin_amdgcn_mfma_f32_16x16x32_bf16(ah, bl[0][dc], acc[i][0], 0, 0, 0);
        acc[i][1] = __builtin_amdgcn_mfma_f32_16x16x32_bf16(ah, bl[1][dc], acc[i][1], 0, 0, 0);
        acc[i][0] = __builtin_amdgcn_mfma_f32_16x16x32_bf16(al, bh[0][dc], acc[i][0], 0, 0, 0);
        acc[i][1] = __builtin_amdgcn_mfma_f32_16x16x32_bf16(al, bh[1][dc], acc[i][1], 0, 0, 0);
      }
      buf ^= 1;
    }
    int kb = cs*4096 + kt*128;
    float wv[16];
    #pragma unroll
    for (int n = 0; n < 16; ++n) wv[n] = w2all[kt*128 + wxc*64 + (n>>2)*16 + g*4 + (n&3)];
    float codeAcc[16];
    #pragma unroll
    for (int n = 0; n < 16; ++n) codeAcc[n] = 0.f;
    #pragma unroll
    for (int jr = 0; jr < 2; ++jr)
      #pragma unroll
      for (int i = 0; i < 4; ++i)
        #pragma unroll
        for (int v = 0; v < 4; ++v) {
          float x = 200.f*acc[i][jr][v] - 100.f*wv[i*4+v];
          float p = __expf(x - m_[jr]) * invS[jr];
          ent -= p * (x - mls[jr]);
          codeAcc[i*4+v] += p;
        }
    #pragma unroll
    for (int n = 0; n < 16; ++n) {
      float s = codeAcc[n];
      s += __shfl_xor(s, 1, 64);
      s += __shfl_xor(s, 2, 64);
      s += __shfl_xor(s, 4, 64);
      s += __shfl_xor(s, 8, 64);
      if (lr == 0) avgLds[wy][wxc*64 + (n>>2)*16 + g*4 + (n&3)] = s;
    }
    __syncthreads();
    if (t < 128) atomicAdd(&avgp[kb + t], (avgLds[0][t] + avgLds[1][t]) * (1.f/16384.f));
  }
  red[t] = ent;
  __syncthreads();
  for (int s2 = 128; s2; s2 >>= 1) { if (t < s2) red[t] += red[t + s2]; __syncthreads(); }
  if (t == 0) atomicAdd(&scal[1], red[0]);
}

// gather q = wn[idx], codebook loss, write z_q channel-first
__global__ __launch_bounds__(256) void k5_gather(const float* __restrict__ zn,
    const float* __restrict__ wn, const int* __restrict__ row_idx,
    float* __restrict__ out_zq, float* __restrict__ scal) {
  __shared__ float tile[256][33];
  __shared__ float red4[4];
  __shared__ float red[256];
  int bh = blockIdx.x, t = threadIdx.x;
  int b = bh >> 5, h = bh & 31;
  float cb = 0.f;
  for (int w = 0; w < 32; ++w) {
    int r = bh*32 + w;
    int idx = row_idx[r];
    float q = wn[(size_t)idx*256 + t];
    float s = q*q;
    #pragma unroll
    for (int mask = 32; mask; mask >>= 1) s += __shfl_xor(s, mask, 64);
    if ((t & 63) == 0) red4[t >> 6] = s;
    __syncthreads();
    float tot = red4[0] + red4[1] + red4[2] + red4[3];
    float inv = 1.f / fmaxf(sqrtf(tot), 1e-6f);
    float zv = zn[(size_t)r*256 + t];
    float d = q*inv - zv;
    cb += d*d;
    tile[t][w] = q;
    __syncthreads();
  }
  red[t] = cb;
  __syncthreads();
  for (int s2 = 128; s2; s2 >>= 1) { if (t < s2) red[t] += red[t+s2]; __syncthreads(); }
  if (t == 0) atomicAdd(&scal[0], red[0]);
  float* ob = out_zq + (size_t)b*256*1024 + (size_t)h*32;
  for (int j = 0; j < 32; ++j) {
    int i = t + j*256; int c = i >> 5, ww = i & 31;
    ob[(size_t)c*1024 + ww] = tile[c][ww];
  }
}

// finalize scalars + emit indices as float
__global__ __launch_bounds__(256) void k6_final(const float* __restrict__ avg_probs,
    const float* __restrict__ scal, const int* __restrict__ row_idx,
    float* __restrict__ out) {
  int t = threadIdx.x;
  if (blockIdx.x < 64) {
    int r = blockIdx.x*256 + t;
    out[4194307 + r] = (float)row_idx[r];
    return;
  }
  __shared__ float red[256];
  float s = 0.f;
  for (int j = 0; j < 32; ++j) {
    float v = avg_probs[t + j*256];
    s -= v * logf(v + 1e-5f);
  }
  red[t] = s;
  __syncthreads();
  for (int q = 128; q; q >>= 1) { if (t < q) red[t] += red[t+q]; __syncthreads(); }
  if (t == 0) {
    float avg_entropy = red[0];
    float sample_entropy = scal[1] * (1.f/16384.f);
    float cb = scal[0] * (1.f/4194304.f);
    out[4194304] = cb;
    out[4194305] = 0.25f * cb;
    out[4194306] = 0.1f * (sample_entropy - avg_entropy);
  }
}

extern "C" void kernel_launch(void* const* d_in, const int* in_sizes, int n_in,
                              void* d_out, int out_size, void* d_ws, size_t ws_size,
                              hipStream_t stream) {
  const float* z   = (const float*)d_in[0];
  const float* emb = (const float*)d_in[1];
  const float* pw  = (const float*)d_in[2];
  const float* pb  = (const float*)d_in[3];
  float* ws  = (float*)d_ws;
  float* out = (float*)d_out;
  float* wn   = ws + OFF_WN;
  float* w2   = ws + OFF_W2;
  float* zn   = ws + OFF_ZN;
  u16*   wnh  = (u16*)(ws + OFF_WNH);
  u16*   wnl  = (u16*)(ws + OFF_WNL);
  u16*   znh  = (u16*)(ws + OFF_ZNH);
  u16*   znl  = (u16*)(ws + OFF_ZNL);
  float* pL1  = ws + OFF_PL1;
  float* pL2  = ws + OFF_PL2;
  float* pS   = ws + OFF_PS;
  int*   pI1  = (int*)(ws + OFF_PI1);
  int*   pI2  = (int*)(ws + OFF_PI2);
  float* rm   = ws + OFF_RM;
  float* rs   = ws + OFF_RS;
  int*   ridx = (int*)(ws + OFF_RIDX);
  float* avgp = ws + OFF_AVGP;
  float* scal = ws + OFF_SCAL;

  k0_init<<<32, 256, 0, stream>>>(ws);
  k1_codebook<<<NCODES, 256, 0, stream>>>(emb, pw, pb, wn, w2, wnh, wnl);
  k2_zn<<<512, 256, 0, stream>>>(z, zn, znh, znl);
  k3_pass1<<<512, 256, 0, stream>>>(znh, znl, wnh, wnl, w2, pL1, pL2, pS, pI1, pI2);
  k3b_refine<<<NROWS/4, 256, 0, stream>>>(zn, wn, w2, pL1, pL2, pS, pI1, pI2, rm, rs, ridx);
  k4_pass2<<<512, 256, 0, stream>>>(znh, znl, wnh, wnl, w2, rm, rs, avgp, scal);
  k5_gather<<<512, 256, 0, stream>>>(zn, wn, ridx, out, scal);
  k6_final<<<65, 256, 0, stream>>>(avgp, scal, ridx, out);
}

// Round 8
// 990.285 us; speedup vs baseline: 63.6161x; 1.4122x over previous
//
#include <hip/hip_runtime.h>
#include <math.h>

// Problem constants
#define NROWS 16384      // B*H*W = 16*32*32
#define NCODES 8192
#define DIMS 256

// ws layout (float offsets)
#define OFF_WN   0u          // fp32 wn       8192*256
#define OFF_W2   2097152u    // fp32 w2       8192
#define OFF_ZN   2105344u    // fp32 zn       16384*256
#define OFF_WNH  6299648u    // ushort wn_hi  8192*256   (1,048,576 floats)
#define OFF_WNL  7348224u    // ushort wn_lo
#define OFF_ZNH  8396800u    // ushort zn_hi  16384*256  (2,097,152 floats)
#define OFF_ZNL  10493952u   // ushort zn_lo
#define OFF_PL1  12591104u   // [2][16384] partial top1 logit
#define OFF_PL2  12623872u   // [2][16384] partial top2 logit
#define OFF_PS   12656640u   // [2][16384] partial sum-exp
#define OFF_PI1  12689408u   // [2][16384] partial top1 idx (int)
#define OFF_PI2  12722176u   // [2][16384] partial top2 idx (int)
#define OFF_RM   12754944u   // 16384 final row max-logit
#define OFF_RS   12771328u   // 16384 final row sum-exp
#define OFF_RIDX 12787712u   // 16384 final exact argmin (int)
#define OFF_AVGP 12804096u   // 8192 avg_probs
#define OFF_SCAL 12812288u   // [0]=cb_sum [1]=ent_sum

typedef __attribute__((ext_vector_type(8))) short bf16x8;
typedef __attribute__((ext_vector_type(4))) float f32x4;
typedef unsigned short u16;

__device__ __forceinline__ u16 f2bf(float f) {          // RNE float->bf16 (finite inputs)
  unsigned u = __float_as_uint(f);
  u += 0x7fffu + ((u >> 16) & 1u);
  return (u16)(u >> 16);
}
__device__ __forceinline__ float bf2f(u16 s) { return __uint_as_float(((unsigned)s) << 16); }

// async global->LDS, 16B per lane; LDS dest is wave-uniform base + lane*16
__device__ __forceinline__ void gl_lds16(const u16* g, u16* l) {
  __builtin_amdgcn_global_load_lds(
      (const __attribute__((address_space(1))) unsigned*)g,
      (__attribute__((address_space(3))) unsigned*)l, 16, 0, 0);
}

// counted-vmcnt phase barrier: oldest stage (4 loads) retired, LDS ops drained,
// then workgroup barrier. Loads for the NEXT phases stay in flight (T4).
#define PHASE_BARRIER_CNT()  asm volatile("s_waitcnt vmcnt(4) lgkmcnt(0)\n\ts_barrier" ::: "memory")
#define PHASE_BARRIER_ALL()  asm volatile("s_waitcnt vmcnt(0) lgkmcnt(0)\n\ts_barrier" ::: "memory")
#define LGKM_BARRIER()       asm volatile("s_waitcnt lgkmcnt(0)\n\ts_barrier" ::: "memory")
#define DRAIN_VM()           asm volatile("s_waitcnt vmcnt(0)" ::: "memory")

// top-2 insert ordered by (value desc, index asc)
__device__ __forceinline__ void ins2(float x, int idx, float& b1, int& i1, float& b2, int& i2) {
  if (x > b1 || (x == b1 && idx < i1)) { b2 = b1; i2 = i1; b1 = x; i1 = idx; }
  else if (x > b2 || (x == b2 && idx < i2)) { b2 = x; i2 = idx; }
}
// tournament combine, same ordering semantics
__device__ __forceinline__ void cmb(float va, int ia, float vb, int ib, float& vo, int& io) {
  bool s = (va > vb) || (va == vb && ia < ib);
  vo = s ? va : vb;
  io = s ? ia : ib;
}

__global__ __launch_bounds__(256) void k0_init(float* ws) {
  int i = blockIdx.x * 256 + threadIdx.x;
  if (i < NCODES) ws[OFF_AVGP + i] = 0.f;
  if (i < 16) ws[OFF_SCAL + i] = 0.f;
}

// weight = emb @ proj_w^T + b ; wn = normalize(weight); w2 = sum(wn^2); + bf16 hi/lo planes
__global__ __launch_bounds__(256) void k1_codebook(const float* __restrict__ emb,
    const float* __restrict__ pw, const float* __restrict__ pb,
    float* __restrict__ wn, float* __restrict__ w2,
    u16* __restrict__ wnh, u16* __restrict__ wnl) {
  __shared__ float e[256];
  __shared__ float red[256];
  int k = blockIdx.x, t = threadIdx.x;
  e[t] = emb[(size_t)k * 256 + t];
  __syncthreads();
  const float4* prow = reinterpret_cast<const float4*>(pw + (size_t)t * 256);
  float acc = pb[t];
  #pragma unroll 8
  for (int q = 0; q < 64; ++q) {
    float4 p4 = prow[q];
    acc += e[q*4+0]*p4.x + e[q*4+1]*p4.y + e[q*4+2]*p4.z + e[q*4+3]*p4.w;
  }
  red[t] = acc * acc;
  __syncthreads();
  for (int s = 128; s; s >>= 1) { if (t < s) red[t] += red[t+s]; __syncthreads(); }
  float inv = 1.f / fmaxf(sqrtf(red[0]), 1e-6f);
  float v = acc * inv;
  size_t o = (size_t)k*256 + t;
  wn[o] = v;
  u16 hb = f2bf(v); float hf = bf2f(hb);
  wnh[o] = hb; wnl[o] = f2bf(v - hf);
  __syncthreads();
  red[t] = v * v;
  __syncthreads();
  for (int s = 128; s; s >>= 1) { if (t < s) red[t] += red[t+s]; __syncthreads(); }
  if (t == 0) w2[k] = red[0];
}

// zn = normalize over channel dim; z is [B,C,H,W]; zn row-major [row][C] + bf16 hi/lo
__global__ __launch_bounds__(256) void k2_zn(const float* __restrict__ z,
    float* __restrict__ zn, u16* __restrict__ znh, u16* __restrict__ znl) {
  __shared__ float tile[256][33];
  __shared__ float inv[32];
  int bh = blockIdx.x, t = threadIdx.x;
  const float* zb = z + (size_t)(bh >> 5) * (256*1024) + (size_t)(bh & 31) * 32;
  for (int j = 0; j < 32; ++j) {
    int i = t + j*256; int c = i >> 5, w = i & 31;
    tile[c][w] = zb[(size_t)c*1024 + w];
  }
  __syncthreads();
  if (t < 32) {
    float s = 0.f;
    for (int c = 0; c < 256; ++c) { float v = tile[c][t]; s += v*v; }
    inv[t] = 1.f / fmaxf(sqrtf(s), 1e-6f);
  }
  __syncthreads();
  size_t base = (size_t)bh * 32 * 256;
  for (int w = 0; w < 32; ++w) {
    float v = tile[t][w] * inv[w];
    size_t o = base + (size_t)w*256 + t;
    zn[o] = v;
    u16 hb = f2bf(v); float hf = bf2f(hb);
    znh[o] = hb; znl[o] = f2bf(v - hf);
  }
}

// ---- Pass 1 (MFMA): per-row online (max logit, sum exp, approx top-2). ----
// logit = 200*dot - 100*w2[k]. Split-bf16: hh + hl + lh (drop ll).
// Rows (B-operand) in registers; codes via global_load_lds into a 3-buffer LDS
// ring with counted vmcnt(4) + raw s_barrier per phase (loads stay in flight
// across barriers, T4). stage(s+2) is issued AFTER the phase barrier: its
// target buf (s+2)%3 == (s-1)%3, whose readers all passed this barrier.
// cs = blockIdx&1: under blockIdx%8->XCD mapping, all blocks on an XCD read
// the SAME 4MB code slice -> fits one per-XCD L2.
__global__ __attribute__((amdgpu_flat_work_group_size(256,256)))
__attribute__((amdgpu_waves_per_eu(2,2))) void k3_pass1(
    const u16* __restrict__ znh, const u16* __restrict__ znl,
    const u16* __restrict__ wnh, const u16* __restrict__ wnl,
    const float* __restrict__ w2,
    float* __restrict__ pL1, float* __restrict__ pL2, float* __restrict__ pS,
    int* __restrict__ pI1, int* __restrict__ pI2) {
  __shared__ u16 Cbuf[3][2][128*32];    // 3-buffer ring, 48 KiB
  __shared__ float w2all[4096];         // 16 KiB
  __shared__ float mrgF[2][2][32][3];
  __shared__ int   mrgI[2][2][32][2];
  int t = threadIdx.x;
  int rb = blockIdx.x >> 1, cs = blockIdx.x & 1;
  int r0 = rb * 64;
  int w = t >> 6, l = t & 63;
  int wxc = w & 1, wy = w >> 1;
  int g = l >> 4, lr = l & 15;

  // B-fragments (rows) -> registers, once
  bf16x8 bh[2][8], bl[2][8];
  #pragma unroll
  for (int jr = 0; jr < 2; ++jr) {
    size_t rbase = (size_t)(r0 + wy*32 + jr*16 + lr) * 256;
    #pragma unroll
    for (int dc = 0; dc < 8; ++dc) {
      bh[jr][dc] = *(const bf16x8*)&znh[rbase + dc*32 + g*8];
      bl[jr][dc] = *(const bf16x8*)&znl[rbase + dc*32 + g*8];
    }
  }
  for (int i = t; i < 4096; i += 256) w2all[i] = w2[cs*4096 + i];

  const size_t csbase = (size_t)cs * 4096 * 256;
  auto stage = [&](int s, int b) {
    int dc2 = s & 7;
    int krow = (s >> 3) * 128;
    #pragma unroll
    for (int rnd = 0; rnd < 2; ++rnd) {
      int i = rnd*256 + t;
      int code = i >> 2, q = i & 3;
      size_t go = csbase + (size_t)(krow + code)*256 + dc2*32 + q*8;
      gl_lds16(&wnh[go], &Cbuf[b][0][rnd*2048 + w*512]);
      gl_lds16(&wnl[go], &Cbuf[b][1][rnd*2048 + w*512]);
    }
  };
  DRAIN_VM();               // clean vmcnt: only stage loads counted inside the loop
  stage(0, 0);
  stage(1, 1);

  float rL1[2] = {-3.0e38f, -3.0e38f}, rL2[2] = {-3.0e38f, -3.0e38f}, rSv[2] = {0.f, 0.f};
  int rI1[2] = {0x7fffffff, 0x7fffffff}, rI2[2] = {0x7fffffff, 0x7fffffff};

  for (int kt = 0; kt < 32; ++kt) {
    f32x4 acc[4][2];
    #pragma unroll
    for (int i = 0; i < 4; ++i) { acc[i][0] = (f32x4){0.f,0.f,0.f,0.f}; acc[i][1] = (f32x4){0.f,0.f,0.f,0.f}; }
    #pragma unroll
    for (int dc = 0; dc < 8; ++dc) {
      int s = kt*8 + dc;
      if (s < 255) PHASE_BARRIER_CNT(); else PHASE_BARRIER_ALL();
      if (s + 2 < 256) {
        int bS = s + 2; bS -= (bS/3)*3;   // (s+2)%3
        stage(s + 2, bS);
      }
      int bR = s - (s/3)*3;               // s%3
      #pragma unroll
      for (int i = 0; i < 4; ++i) {
        int co = (wxc*64 + i*16 + lr)*32 + g*8;
        bf16x8 ah = *(const bf16x8*)&Cbuf[bR][0][co];
        bf16x8 al = *(const bf16x8*)&Cbuf[bR][1][co];
        acc[i][0] = __builtin_amdgcn_mfma_f32_16x16x32_bf16(ah, bh[0][dc], acc[i][0], 0, 0, 0);
        acc[i][1] = __builtin_amdgcn_mfma_f32_16x16x32_bf16(ah, bh[1][dc], acc[i][1], 0, 0, 0);
        acc[i][0] = __builtin_amdgcn_mfma_f32_16x16x32_bf16(ah, bl[0][dc], acc[i][0], 0, 0, 0);
        acc[i][1] = __builtin_amdgcn_mfma_f32_16x16x32_bf16(ah, bl[1][dc], acc[i][1], 0, 0, 0);
        acc[i][0] = __builtin_amdgcn_mfma_f32_16x16x32_bf16(al, bh[0][dc], acc[i][0], 0, 0, 0);
        acc[i][1] = __builtin_amdgcn_mfma_f32_16x16x32_bf16(al, bh[1][dc], acc[i][1], 0, 0, 0);
      }
    }
    // per-kt stats: tournament-tree top2 (exact (value desc, idx asc) order)
    int kb = cs*4096 + kt*128;
    float wv[16];
    #pragma unroll
    for (int n = 0; n < 16; ++n) wv[n] = w2all[kt*128 + wxc*64 + (n>>2)*16 + g*4 + (n&3)];
    #pragma unroll
    for (int jr = 0; jr < 2; ++jr) {
      float x[16]; int ix[16];
      #pragma unroll
      for (int n = 0; n < 16; ++n) {
        x[n] = 200.f*acc[n>>2][jr][n&3] - 100.f*wv[n];
        ix[n] = kb + wxc*64 + (n>>2)*16 + g*4 + (n&3);
      }
      float v8[8]; int i8_[8];
      #pragma unroll
      for (int n = 0; n < 8; ++n) cmb(x[n], ix[n], x[n+8], ix[n+8], v8[n], i8_[n]);
      float v4[4]; int i4_[4];
      #pragma unroll
      for (int n = 0; n < 4; ++n) cmb(v8[n], i8_[n], v8[n+4], i8_[n+4], v4[n], i4_[n]);
      float v2a, v2b; int i2a, i2b;
      cmb(v4[0], i4_[0], v4[2], i4_[2], v2a, i2a);
      cmb(v4[1], i4_[1], v4[3], i4_[3], v2b, i2b);
      float b1; int i1;
      cmb(v2a, i2a, v2b, i2b, b1, i1);
      // second place: mask winner, re-tree
      float y[16];
      #pragma unroll
      for (int n = 0; n < 16; ++n) y[n] = (ix[n] == i1) ? -3.0e38f : x[n];
      #pragma unroll
      for (int n = 0; n < 8; ++n) cmb(y[n], ix[n], y[n+8], ix[n+8], v8[n], i8_[n]);
      #pragma unroll
      for (int n = 0; n < 4; ++n) cmb(v8[n], i8_[n], v8[n+4], i8_[n+4], v4[n], i4_[n]);
      cmb(v4[0], i4_[0], v4[2], i4_[2], v2a, i2a);
      cmb(v4[1], i4_[1], v4[3], i4_[3], v2b, i2b);
      float b2; int i2;
      cmb(v2a, i2a, v2b, i2b, b2, i2);
      // sum exp (pairwise)
      float es[8];
      #pragma unroll
      for (int n = 0; n < 8; ++n) es[n] = __expf(x[n] - b1) + __expf(x[n+8] - b1);
      #pragma unroll
      for (int n = 0; n < 4; ++n) es[n] += es[n+4];
      float S = (es[0] + es[1]) + (es[2] + es[3]);
      // lanes l^16, l^32 share this row (same lr), hold other codes: butterfly merge
      #pragma unroll
      for (int mask = 16; mask <= 32; mask <<= 1) {
        float ob1 = __shfl_xor(b1, mask, 64);
        float ob2 = __shfl_xor(b2, mask, 64);
        float oS  = __shfl_xor(S,  mask, 64);
        int   oi1 = __shfl_xor(i1, mask, 64);
        int   oi2 = __shfl_xor(i2, mask, 64);
        float pb1 = b1;
        ins2(ob1, oi1, b1, i1, b2, i2);
        ins2(ob2, oi2, b1, i1, b2, i2);
        S = S * __expf(pb1 - b1) + oS * __expf(ob1 - b1);
      }
      float pr = rL1[jr];
      ins2(b1, i1, rL1[jr], rI1[jr], rL2[jr], rI2[jr]);
      ins2(b2, i2, rL1[jr], rI1[jr], rL2[jr], rI2[jr]);
      rSv[jr] = rSv[jr] * __expf(pr - rL1[jr]) + S * __expf(b1 - rL1[jr]);
    }
  }
  // merge the two code-half waves (same rows) via LDS, write per-(cs) partials
  __syncthreads();
  if (g == 0) {
    #pragma unroll
    for (int jr = 0; jr < 2; ++jr) {
      int ri = jr*16 + lr;
      mrgF[wy][wxc][ri][0] = rL1[jr]; mrgF[wy][wxc][ri][1] = rL2[jr]; mrgF[wy][wxc][ri][2] = rSv[jr];
      mrgI[wy][wxc][ri][0] = rI1[jr]; mrgI[wy][wxc][ri][1] = rI2[jr];
    }
  }
  __syncthreads();
  if (t < 64) {
    int wyy = t >> 5, ri = t & 31;
    float b1 = mrgF[wyy][0][ri][0], b2 = mrgF[wyy][0][ri][1], S = mrgF[wyy][0][ri][2];
    int i1 = mrgI[wyy][0][ri][0], i2 = mrgI[wyy][0][ri][1];
    float ob1 = mrgF[wyy][1][ri][0], ob2 = mrgF[wyy][1][ri][1], oS = mrgF[wyy][1][ri][2];
    int oi1 = mrgI[wyy][1][ri][0], oi2 = mrgI[wyy][1][ri][1];
    float pb1 = b1;
    ins2(ob1, oi1, b1, i1, b2, i2);
    ins2(ob2, oi2, b1, i1, b2, i2);
    S = S * __expf(pb1 - b1) + oS * __expf(ob1 - b1);
    int r = r0 + wyy*32 + ri;
    size_t o = (size_t)cs * NROWS + r;
    pL1[o] = b1; pL2[o] = b2; pS[o] = S;
    pI1[o] = i1; pI2[o] = i2;
  }
}

// merge code-half partials; exact fp32 re-score of top-2 -> final argmin, row max, sum
__global__ __launch_bounds__(256) void k3b_refine(
    const float* __restrict__ zn, const float* __restrict__ wn, const float* __restrict__ w2,
    const float* __restrict__ pL1, const float* __restrict__ pL2, const float* __restrict__ pS,
    const int* __restrict__ pI1, const int* __restrict__ pI2,
    float* __restrict__ rm, float* __restrict__ rs, int* __restrict__ ridx) {
  int t = threadIdx.x;
  int r = blockIdx.x * 4 + (t >> 6);
  int l = t & 63;
  float b1 = pL1[r], b2 = pL2[r], S = pS[r];
  int i1 = pI1[r], i2 = pI2[r];
  float ob1 = pL1[NROWS + r], ob2 = pL2[NROWS + r], oS = pS[NROWS + r];
  int oi1 = pI1[NROWS + r], oi2 = pI2[NROWS + r];
  float pb1 = b1;
  ins2(ob1, oi1, b1, i1, b2, i2);
  ins2(ob2, oi2, b1, i1, b2, i2);
  S = S * __expf(pb1 - b1) + oS * __expf(ob1 - b1);
  int cand = (l < 32) ? i1 : i2;
  int lo = l & 31;
  const float* zr = zn + (size_t)r * 256;
  const float* wc = wn + (size_t)cand * 256;
  float d = 0.f;
  #pragma unroll
  for (int q = 0; q < 8; ++q) d += zr[lo + q*32] * wc[lo + q*32];
  #pragma unroll
  for (int mask = 1; mask <= 16; mask <<= 1) d += __shfl_xor(d, mask, 64);
  float dOther = __shfl_xor(d, 32, 64);
  if (l == 0) {
    float s1 = w2[i1] - 2.f*d;       // z2 common term dropped
    float s2 = w2[i2] - 2.f*dOther;
    int win = i1;
    if (s2 < s1 || (s2 == s1 && i2 < i1)) win = i2;
    rm[r] = b1; rs[r] = S; ridx[r] = win;
  }
}

// ---- Pass 2 (MFMA): recompute logits; avg_probs + sample entropy ----
__global__ __attribute__((amdgpu_flat_work_group_size(256,256)))
__attribute__((amdgpu_waves_per_eu(2,2))) void k4_pass2(
    const u16* __restrict__ znh, const u16* __restrict__ znl,
    const u16* __restrict__ wnh, const u16* __restrict__ wnl,
    const float* __restrict__ w2,
    const float* __restrict__ rm, const float* __restrict__ rs,
    float* __restrict__ avgp, float* __restrict__ scal) {
  __shared__ u16 Cbuf[3][2][128*32];
  __shared__ float w2all[4096];
  __shared__ float avgLds[2][128];
  __shared__ float red[256];
  int t = threadIdx.x;
  int rb = blockIdx.x >> 1, cs = blockIdx.x & 1;
  int r0 = rb * 64;
  int w = t >> 6, l = t & 63;
  int wxc = w & 1, wy = w >> 1;
  int g = l >> 4, lr = l & 15;

  bf16x8 bh[2][8], bl[2][8];
  #pragma unroll
  for (int jr = 0; jr < 2; ++jr) {
    size_t rbase = (size_t)(r0 + wy*32 + jr*16 + lr) * 256;
    #pragma unroll
    for (int dc = 0; dc < 8; ++dc) {
      bh[jr][dc] = *(const bf16x8*)&znh[rbase + dc*32 + g*8];
      bl[jr][dc] = *(const bf16x8*)&znl[rbase + dc*32 + g*8];
    }
  }
  for (int i = t; i < 4096; i += 256) w2all[i] = w2[cs*4096 + i];

  float m_[2], invS[2], mls[2];
  #pragma unroll
  for (int jr = 0; jr < 2; ++jr) {
    int r = r0 + wy*32 + jr*16 + lr;
    float mm = rm[r], ss = rs[r];
    m_[jr] = mm; invS[jr] = 1.f / ss; mls[jr] = mm + __logf(ss);
  }

  const size_t csbase = (size_t)cs * 4096 * 256;
  auto stage = [&](int s, int b) {
    int dc2 = s & 7;
    int krow = (s >> 3) * 128;
    #pragma unroll
    for (int rnd = 0; rnd < 2; ++rnd) {
      int i = rnd*256 + t;
      int code = i >> 2, q = i & 3;
      size_t go = csbase + (size_t)(krow + code)*256 + dc2*32 + q*8;
      gl_lds16(&wnh[go], &Cbuf[b][0][rnd*2048 + w*512]);
      gl_lds16(&wnl[go], &Cbuf[b][1][rnd*2048 + w*512]);
    }
  };
  DRAIN_VM();
  stage(0, 0);
  stage(1, 1);
  float ent = 0.f;

  for (int kt = 0; kt < 32; ++kt) {
    f32x4 acc[4][2];
    #pragma unroll
    for (int i = 0; i < 4; ++i) { acc[i][0] = (f32x4){0.f,0.f,0.f,0.f}; acc[i][1] = (f32x4){0.f,0.f,0.f,0.f}; }
    #pragma unroll
    for (int dc = 0; dc < 8; ++dc) {
      int s = kt*8 + dc;
      if (s < 255) PHASE_BARRIER_CNT(); else PHASE_BARRIER_ALL();
      if (s + 2 < 256) {
        int bS = s + 2; bS -= (bS/3)*3;
        stage(s + 2, bS);
      }
      int bR = s - (s/3)*3;
      #pragma unroll
      for (int i = 0; i < 4; ++i) {
        int co = (wxc*64 + i*16 + lr)*32 + g*8;
        bf16x8 ah = *(const bf16x8*)&Cbuf[bR][0][co];
        bf16x8 al = *(const bf16x8*)&Cbuf[bR][1][co];
        acc[i][0] = __builtin_amdgcn_mfma_f32_16x16x32_bf16(ah, bh[0][dc], acc[i][0], 0, 0, 0);
        acc[i][1] = __builtin_amdgcn_mfma_f32_16x16x32_bf16(ah, bh[1][dc], acc[i][1], 0, 0, 0);
        acc[i][0] = __builtin_amdgcn_mfma_f32_16x16x32_bf16(ah, bl[0][dc], acc[i][0], 0, 0, 0);
        acc[i][1] = __builtin_amdgcn_mfma_f32_16x16x32_bf16(ah, bl[1][dc], acc[i][1], 0, 0, 0);
        acc[i][0] = __builtin_amdgcn_mfma_f32_16x16x32_bf16(al, bh[0][dc], acc[i][0], 0, 0, 0);
        acc[i][1] = __builtin_amdgcn_mfma_f32_16x16x32_bf16(al, bh[1][dc], acc[i][1], 0, 0, 0);
      }
    }
    int kb = cs*4096 + kt*128;
    float wv[16];
    #pragma unroll
    for (int n = 0; n < 16; ++n) wv[n] = w2all[kt*128 + wxc*64 + (n>>2)*16 + g*4 + (n&3)];
    float codeAcc[16];
    #pragma unroll
    for (int n = 0; n < 16; ++n) codeAcc[n] = 0.f;
    #pragma unroll
    for (int jr = 0; jr < 2; ++jr)
      #pragma unroll
      for (int i = 0; i < 4; ++i)
        #pragma unroll
        for (int v = 0; v < 4; ++v) {
          float x = 200.f*acc[i][jr][v] - 100.f*wv[i*4+v];
          float p = __expf(x - m_[jr]) * invS[jr];
          ent -= p * (x - mls[jr]);
          codeAcc[i*4+v] += p;
        }
    #pragma unroll
    for (int n = 0; n < 16; ++n) {
      float s = codeAcc[n];
      s += __shfl_xor(s, 1, 64);
      s += __shfl_xor(s, 2, 64);
      s += __shfl_xor(s, 4, 64);
      s += __shfl_xor(s, 8, 64);
      if (lr == 0) avgLds[wy][wxc*64 + (n>>2)*16 + g*4 + (n&3)] = s;
    }
    LGKM_BARRIER();       // publish avgLds without draining the load pipeline
    if (t < 128) atomicAdd(&avgp[kb + t], (avgLds[0][t] + avgLds[1][t]) * (1.f/16384.f));
  }
  red[t] = ent;
  __syncthreads();
  for (int s2 = 128; s2; s2 >>= 1) { if (t < s2) red[t] += red[t + s2]; __syncthreads(); }
  if (t == 0) atomicAdd(&scal[1], red[0]);
}

// gather q = wn[idx], codebook loss, write z_q channel-first
__global__ __launch_bounds__(256) void k5_gather(const float* __restrict__ zn,
    const float* __restrict__ wn, const int* __restrict__ row_idx,
    float* __restrict__ out_zq, float* __restrict__ scal) {
  __shared__ float tile[256][33];
  __shared__ float red4[4];
  __shared__ float red[256];
  int bh = blockIdx.x, t = threadIdx.x;
  int b = bh >> 5, h = bh & 31;
  float cb = 0.f;
  for (int w = 0; w < 32; ++w) {
    int r = bh*32 + w;
    int idx = row_idx[r];
    float q = wn[(size_t)idx*256 + t];
    float s = q*q;
    #pragma unroll
    for (int mask = 32; mask; mask >>= 1) s += __shfl_xor(s, mask, 64);
    if ((t & 63) == 0) red4[t >> 6] = s;
    __syncthreads();
    float tot = red4[0] + red4[1] + red4[2] + red4[3];
    float inv = 1.f / fmaxf(sqrtf(tot), 1e-6f);
    float zv = zn[(size_t)r*256 + t];
    float d = q*inv - zv;
    cb += d*d;
    tile[t][w] = q;
    __syncthreads();
  }
  red[t] = cb;
  __syncthreads();
  for (int s2 = 128; s2; s2 >>= 1) { if (t < s2) red[t] += red[t+s2]; __syncthreads(); }
  if (t == 0) atomicAdd(&scal[0], red[0]);
  float* ob = out_zq + (size_t)b*256*1024 + (size_t)h*32;
  for (int j = 0; j < 32; ++j) {
    int i = t + j*256; int c = i >> 5, ww = i & 31;
    ob[(size_t)c*1024 + ww] = tile[c][ww];
  }
}

// finalize scalars + emit indices as float
__global__ __launch_bounds__(256) void k6_final(const float* __restrict__ avg_probs,
    const float* __restrict__ scal, const int* __restrict__ row_idx,
    float* __restrict__ out) {
  int t = threadIdx.x;
  if (blockIdx.x < 64) {
    int r = blockIdx.x*256 + t;
    out[4194307 + r] = (float)row_idx[r];
    return;
  }
  __shared__ float red[256];
  float s = 0.f;
  for (int j = 0; j < 32; ++j) {
    float v = avg_probs[t + j*256];
    s -= v * logf(v + 1e-5f);
  }
  red[t] = s;
  __syncthreads();
  for (int q = 128; q; q >>= 1) { if (t < q) red[t] += red[t+q]; __syncthreads(); }
  if (t == 0) {
    float avg_entropy = red[0];
    float sample_entropy = scal[1] * (1.f/16384.f);
    float cb = scal[0] * (1.f/4194304.f);
    out[4194304] = cb;
    out[4194305] = 0.25f * cb;
    out[4194306] = 0.1f * (sample_entropy - avg_entropy);
  }
}

extern "C" void kernel_launch(void* const* d_in, const int* in_sizes, int n_in,
                              void* d_out, int out_size, void* d_ws, size_t ws_size,
                              hipStream_t stream) {
  const float* z   = (const float*)d_in[0];
  const float* emb = (const float*)d_in[1];
  const float* pw  = (const float*)d_in[2];
  const float* pb  = (const float*)d_in[3];
  float* ws  = (float*)d_ws;
  float* out = (float*)d_out;
  float* wn   = ws + OFF_WN;
  float* w2   = ws + OFF_W2;
  float* zn   = ws + OFF_ZN;
  u16*   wnh  = (u16*)(ws + OFF_WNH);
  u16*   wnl  = (u16*)(ws + OFF_WNL);
  u16*   znh  = (u16*)(ws + OFF_ZNH);
  u16*   znl  = (u16*)(ws + OFF_ZNL);
  float* pL1  = ws + OFF_PL1;
  float* pL2  = ws + OFF_PL2;
  float* pS   = ws + OFF_PS;
  int*   pI1  = (int*)(ws + OFF_PI1);
  int*   pI2  = (int*)(ws + OFF_PI2);
  float* rm   = ws + OFF_RM;
  float* rs   = ws + OFF_RS;
  int*   ridx = (int*)(ws + OFF_RIDX);
  float* avgp = ws + OFF_AVGP;
  float* scal = ws + OFF_SCAL;

  k0_init<<<32, 256, 0, stream>>>(ws);
  k1_codebook<<<NCODES, 256, 0, stream>>>(emb, pw, pb, wn, w2, wnh, wnl);
  k2_zn<<<512, 256, 0, stream>>>(z, zn, znh, znl);
  k3_pass1<<<512, 256, 0, stream>>>(znh, znl, wnh, wnl, w2, pL1, pL2, pS, pI1, pI2);
  k3b_refine<<<NROWS/4, 256, 0, stream>>>(zn, wn, w2, pL1, pL2, pS, pI1, pI2, rm, rs, ridx);
  k4_pass2<<<512, 256, 0, stream>>>(znh, znl, wnh, wnl, w2, rm, rs, avgp, scal);
  k5_gather<<<512, 256, 0, stream>>>(zn, wn, ridx, out, scal);
  k6_final<<<65, 256, 0, stream>>>(avgp, scal, ridx, out);
}

// Round 11
// 860.723 us; speedup vs baseline: 73.1921x; 1.1505x over previous
//
#include <hip/hip_runtime.h>
#include <math.h>

// Problem constants
#define NROWS 16384      // B*H*W = 16*32*32
#define NCODES 8192
#define DIMS 256
#define NCS 4            // code-slices (2048 codes each); cs = blockIdx&3
#define CEXP 288.5390082f   // 200 * log2(e): logits in exp2-space, y = CEXP*dot

// ws layout (float offsets)
#define OFF_WN   0u          // fp32 wn       8192*256
#define OFF_W2   2097152u    // fp32 w2       8192
#define OFF_ZN   2105344u    // fp32 zn       16384*256
#define OFF_WNH  6299648u    // ushort wn_hi
#define OFF_WNL  7348224u    // ushort wn_lo
#define OFF_ZNH  8396800u    // ushort zn_hi
#define OFF_ZNL  10493952u   // ushort zn_lo
#define OFF_PL1  12591104u   // [4][16384] partial top1 logit (y-space)
#define OFF_PL2  12656640u   // [4][16384] partial top2 logit
#define OFF_PS   12722176u   // [4][16384] partial sum-exp2
#define OFF_PI1  12787712u   // [4][16384] partial top1 idx (int)
#define OFF_PI2  12853248u   // [4][16384] partial top2 idx (int)
#define OFF_RM   12918784u   // 16384 final row max (y-space)
#define OFF_RS   12935168u   // 16384 final row sum-exp2
#define OFF_RIDX 12951552u   // 16384 final exact argmin (int)
#define OFF_AVGP 12967936u   // 8192 avg_probs
#define OFF_SCAL 12976128u   // [0]=cb_sum [1]=ent_sum(nat)

typedef __attribute__((ext_vector_type(8))) short bf16x8;
typedef __attribute__((ext_vector_type(4))) float f32x4;
typedef unsigned short u16;

__device__ __forceinline__ u16 f2bf(float f) {
  unsigned u = __float_as_uint(f);
  u += 0x7fffu + ((u >> 16) & 1u);
  return (u16)(u >> 16);
}
__device__ __forceinline__ float bf2f(u16 s) { return __uint_as_float(((unsigned)s) << 16); }

__device__ __forceinline__ void gl_lds16(const u16* g, u16* l) {
  __builtin_amdgcn_global_load_lds(
      (const __attribute__((address_space(1))) unsigned*)g,
      (__attribute__((address_space(3))) unsigned*)l, 16, 0, 0);
}

#define PHASE_BARRIER_CNT()  asm volatile("s_waitcnt vmcnt(4) lgkmcnt(0)\n\ts_barrier" ::: "memory")
#define PHASE_BARRIER_ALL()  asm volatile("s_waitcnt vmcnt(0) lgkmcnt(0)\n\ts_barrier" ::: "memory")
#define LGKM_BARRIER()       asm volatile("s_waitcnt lgkmcnt(0)\n\ts_barrier" ::: "memory")
#define DRAIN_VM()           asm volatile("s_waitcnt vmcnt(0)" ::: "memory")

// top-2 insert ordered by (value desc, index asc)
__device__ __forceinline__ void ins2(float x, int idx, float& b1, int& i1, float& b2, int& i2) {
  if (x > b1 || (x == b1 && idx < i1)) { b2 = b1; i2 = i1; b1 = x; i1 = idx; }
  else if (x > b2 || (x == b2 && idx < i2)) { b2 = x; i2 = idx; }
}

__global__ __launch_bounds__(256) void k0_init(float* ws) {
  int i = blockIdx.x * 256 + threadIdx.x;
  if (i < NCODES) ws[OFF_AVGP + i] = 0.f;
  if (i < 16) ws[OFF_SCAL + i] = 0.f;
}

// weight = emb @ proj_w^T + b ; wn = normalize; w2 = sum(wn^2); + bf16 hi/lo planes
__global__ __launch_bounds__(256) void k1_codebook(const float* __restrict__ emb,
    const float* __restrict__ pw, const float* __restrict__ pb,
    float* __restrict__ wn, float* __restrict__ w2,
    u16* __restrict__ wnh, u16* __restrict__ wnl) {
  __shared__ float e[256];
  __shared__ float red[256];
  int k = blockIdx.x, t = threadIdx.x;
  e[t] = emb[(size_t)k * 256 + t];
  __syncthreads();
  const float4* prow = reinterpret_cast<const float4*>(pw + (size_t)t * 256);
  float acc = pb[t];
  #pragma unroll 8
  for (int q = 0; q < 64; ++q) {
    float4 p4 = prow[q];
    acc += e[q*4+0]*p4.x + e[q*4+1]*p4.y + e[q*4+2]*p4.z + e[q*4+3]*p4.w;
  }
  red[t] = acc * acc;
  __syncthreads();
  for (int s = 128; s; s >>= 1) { if (t < s) red[t] += red[t+s]; __syncthreads(); }
  float inv = 1.f / fmaxf(sqrtf(red[0]), 1e-6f);
  float v = acc * inv;
  size_t o = (size_t)k*256 + t;
  wn[o] = v;
  u16 hb = f2bf(v); float hf = bf2f(hb);
  wnh[o] = hb; wnl[o] = f2bf(v - hf);
  __syncthreads();
  red[t] = v * v;
  __syncthreads();
  for (int s = 128; s; s >>= 1) { if (t < s) red[t] += red[t+s]; __syncthreads(); }
  if (t == 0) w2[k] = red[0];
}

// zn = normalize over channel dim; zn row-major [row][C] + bf16 hi/lo
__global__ __launch_bounds__(256) void k2_zn(const float* __restrict__ z,
    float* __restrict__ zn, u16* __restrict__ znh, u16* __restrict__ znl) {
  __shared__ float tile[256][33];
  __shared__ float inv[32];
  int bh = blockIdx.x, t = threadIdx.x;
  const float* zb = z + (size_t)(bh >> 5) * (256*1024) + (size_t)(bh & 31) * 32;
  for (int j = 0; j < 32; ++j) {
    int i = t + j*256; int c = i >> 5, w = i & 31;
    tile[c][w] = zb[(size_t)c*1024 + w];
  }
  __syncthreads();
  if (t < 32) {
    float s = 0.f;
    for (int c = 0; c < 256; ++c) { float v = tile[c][t]; s += v*v; }
    inv[t] = 1.f / fmaxf(sqrtf(s), 1e-6f);
  }
  __syncthreads();
  size_t base = (size_t)bh * 32 * 256;
  for (int w = 0; w < 32; ++w) {
    float v = tile[t][w] * inv[w];
    size_t o = base + (size_t)w*256 + t;
    zn[o] = v;
    u16 hb = f2bf(v); float hf = bf2f(hb);
    znh[o] = hb; znl[o] = f2bf(v - hf);
  }
}

// ---- Pass 1 (MFMA): per-row online (max, sum-exp2, per-lane top-2). ----
// y = CEXP*dot (w2 dropped: wn normalized -> w2 == 1 +- 1e-6; shift-invariant
// for softmax/argmax; logit effect ~1e-4, 10x below split-bf16 error; exact
// indices protected by k3b's fp32 re-score WITH w2).
// Split-bf16: hh + hl + lh. T4 ring of 3 LDS bufs, counted vmcnt(4).
// Stats: branchless per-lane top-2 chain (med3 idiom) + exp2-space sumexp;
// all cross-lane/cross-wave merges deferred to once at kernel end.
// cs = blockIdx&3: each XCD's L2 holds one 2MB code slice.
__global__ __attribute__((amdgpu_flat_work_group_size(256,256)))
__attribute__((amdgpu_waves_per_eu(2,2))) void k3_pass1(
    const u16* __restrict__ znh, const u16* __restrict__ znl,
    const u16* __restrict__ wnh, const u16* __restrict__ wnl,
    float* __restrict__ pL1, float* __restrict__ pL2, float* __restrict__ pS,
    int* __restrict__ pI1, int* __restrict__ pI2) {
  __shared__ u16 Cbuf[3][2][128*32];    // 48 KiB ring
  __shared__ float mrgF[2][2][32][3];
  __shared__ int   mrgI[2][2][32][2];
  int t = threadIdx.x;
  int rb = blockIdx.x >> 2, cs = blockIdx.x & 3;
  int r0 = rb * 64;
  int w = t >> 6, l = t & 63;
  int wxc = w & 1, wy = w >> 1;
  int g = l >> 4, lr = l & 15;

  bf16x8 bh[2][8], bl[2][8];
  #pragma unroll
  for (int jr = 0; jr < 2; ++jr) {
    size_t rbase = (size_t)(r0 + wy*32 + jr*16 + lr) * 256;
    #pragma unroll
    for (int dc = 0; dc < 8; ++dc) {
      bh[jr][dc] = *(const bf16x8*)&znh[rbase + dc*32 + g*8];
      bl[jr][dc] = *(const bf16x8*)&znl[rbase + dc*32 + g*8];
    }
  }

  const size_t csbase = (size_t)cs * 2048 * 256;
  auto stage = [&](int s, int b) {
    int dc2 = s & 7;
    int krow = (s >> 3) * 128;
    #pragma unroll
    for (int rnd = 0; rnd < 2; ++rnd) {
      int i = rnd*256 + t;
      int code = i >> 2, q = i & 3;
      size_t go = csbase + (size_t)(krow + code)*256 + dc2*32 + q*8;
      gl_lds16(&wnh[go], &Cbuf[b][0][rnd*2048 + w*512]);
      gl_lds16(&wnl[go], &Cbuf[b][1][rnd*2048 + w*512]);
    }
  };
  DRAIN_VM();
  stage(0, 0);
  stage(1, 1);

  float b1[2] = {-3.0e38f, -3.0e38f}, b2[2] = {-3.0e38f, -3.0e38f}, Sv[2] = {0.f, 0.f};
  int i1[2] = {0, 0}, i2[2] = {0, 0};   // encoded kt*16+n

  for (int kt = 0; kt < 16; ++kt) {
    f32x4 acc[4][2];
    #pragma unroll
    for (int i = 0; i < 4; ++i) { acc[i][0] = (f32x4){0.f,0.f,0.f,0.f}; acc[i][1] = (f32x4){0.f,0.f,0.f,0.f}; }
    #pragma unroll
    for (int dc = 0; dc < 8; ++dc) {
      int s = kt*8 + dc;
      if (s < 127) PHASE_BARRIER_CNT(); else PHASE_BARRIER_ALL();
      if (s + 2 < 128) {
        int bS = s + 2; bS -= (bS/3)*3;
        stage(s + 2, bS);
      }
      int bR = s - (s/3)*3;
      #pragma unroll
      for (int i = 0; i < 4; ++i) {
        int co = (wxc*64 + i*16 + lr)*32 + g*8;
        bf16x8 ah = *(const bf16x8*)&Cbuf[bR][0][co];
        bf16x8 al = *(const bf16x8*)&Cbuf[bR][1][co];
        acc[i][0] = __builtin_amdgcn_mfma_f32_16x16x32_bf16(ah, bh[0][dc], acc[i][0], 0, 0, 0);
        acc[i][1] = __builtin_amdgcn_mfma_f32_16x16x32_bf16(ah, bh[1][dc], acc[i][1], 0, 0, 0);
        acc[i][0] = __builtin_amdgcn_mfma_f32_16x16x32_bf16(ah, bl[0][dc], acc[i][0], 0, 0, 0);
        acc[i][1] = __builtin_amdgcn_mfma_f32_16x16x32_bf16(ah, bl[1][dc], acc[i][1], 0, 0, 0);
        acc[i][0] = __builtin_amdgcn_mfma_f32_16x16x32_bf16(al, bh[0][dc], acc[i][0], 0, 0, 0);
        acc[i][1] = __builtin_amdgcn_mfma_f32_16x16x32_bf16(al, bh[1][dc], acc[i][1], 0, 0, 0);
      }
    }
    // slim per-kt stats: raw-acc top-2 chain + exp2-space sumexp (lane-local)
    int kb16 = kt * 16;
    #pragma unroll
    for (int jr = 0; jr < 2; ++jr) {
      float xv[16];
      #pragma unroll
      for (int n = 0; n < 16; ++n) xv[n] = acc[n>>2][jr][n&3];
      float ob1 = b1[jr];
      #pragma unroll
      for (int n = 0; n < 16; ++n) {
        float x = xv[n];
        bool c1 = x > b1[jr];
        bool c2 = x > b2[jr];
        float hi = fmaxf(x, b1[jr]);
        float lo = fminf(x, b1[jr]);
        b2[jr] = fmaxf(lo, fminf(hi, b2[jr]));
        i2[jr] = c1 ? i1[jr] : (c2 ? (kb16 + n) : i2[jr]);
        b1[jr] = hi;
        i1[jr] = c1 ? (kb16 + n) : i1[jr];
      }
      float negCm = -CEXP * b1[jr];
      float ts0 = 0.f, ts1 = 0.f;
      #pragma unroll
      for (int n = 0; n < 16; n += 2) {
        ts0 += exp2f(fmaf(CEXP, xv[n],   negCm));
        ts1 += exp2f(fmaf(CEXP, xv[n+1], negCm));
      }
      Sv[jr] = Sv[jr] * exp2f(CEXP * (ob1 - b1[jr])) + (ts0 + ts1);
    }
  }
  // decode indices, convert to y-space, merge lanes (g), then waves (wxc)
  float my[2], y2[2]; int gi1[2], gi2[2];
  #pragma unroll
  for (int jr = 0; jr < 2; ++jr) {
    int e1 = i1[jr], e2 = i2[jr];
    int base = cs*2048 + wxc*64 + g*4;
    gi1[jr] = base + (e1>>4)*128 + ((e1&15)>>2)*16 + (e1&3);
    gi2[jr] = base + (e2>>4)*128 + ((e2&15)>>2)*16 + (e2&3);
    my[jr] = CEXP * b1[jr];
    y2[jr] = CEXP * b2[jr];
    #pragma unroll
    for (int mask = 16; mask <= 32; mask <<= 1) {
      float om  = __shfl_xor(my[jr], mask, 64);
      float oy2 = __shfl_xor(y2[jr], mask, 64);
      float oS  = __shfl_xor(Sv[jr], mask, 64);
      int   o1  = __shfl_xor(gi1[jr], mask, 64);
      int   o2  = __shfl_xor(gi2[jr], mask, 64);
      float pm = my[jr];
      ins2(om,  o1, my[jr], gi1[jr], y2[jr], gi2[jr]);
      ins2(oy2, o2, my[jr], gi1[jr], y2[jr], gi2[jr]);
      Sv[jr] = Sv[jr] * exp2f(pm - my[jr]) + oS * exp2f(om - my[jr]);
    }
  }
  __syncthreads();
  if (g == 0) {
    #pragma unroll
    for (int jr = 0; jr < 2; ++jr) {
      int ri = jr*16 + lr;
      mrgF[wy][wxc][ri][0] = my[jr]; mrgF[wy][wxc][ri][1] = y2[jr]; mrgF[wy][wxc][ri][2] = Sv[jr];
      mrgI[wy][wxc][ri][0] = gi1[jr]; mrgI[wy][wxc][ri][1] = gi2[jr];
    }
  }
  __syncthreads();
  if (t < 64) {
    int wyy = t >> 5, ri = t & 31;
    float m1 = mrgF[wyy][0][ri][0], m2 = mrgF[wyy][0][ri][1], S = mrgF[wyy][0][ri][2];
    int a1 = mrgI[wyy][0][ri][0], a2 = mrgI[wyy][0][ri][1];
    float om1 = mrgF[wyy][1][ri][0], om2 = mrgF[wyy][1][ri][1], oS = mrgF[wyy][1][ri][2];
    int ob1i = mrgI[wyy][1][ri][0], ob2i = mrgI[wyy][1][ri][1];
    float pm = m1;
    ins2(om1, ob1i, m1, a1, m2, a2);
    ins2(om2, ob2i, m1, a1, m2, a2);
    S = S * exp2f(pm - m1) + oS * exp2f(om1 - m1);
    int r = r0 + wyy*32 + ri;
    size_t o = (size_t)cs * NROWS + r;
    pL1[o] = m1; pL2[o] = m2; pS[o] = S;
    pI1[o] = a1; pI2[o] = a2;
  }
}

// merge 4 code-slice partials; exact fp32 re-score of top-2 -> final argmin
__global__ __launch_bounds__(256) void k3b_refine(
    const float* __restrict__ zn, const float* __restrict__ wn, const float* __restrict__ w2,
    const float* __restrict__ pL1, const float* __restrict__ pL2, const float* __restrict__ pS,
    const int* __restrict__ pI1, const int* __restrict__ pI2,
    float* __restrict__ rm, float* __restrict__ rs, int* __restrict__ ridx) {
  int t = threadIdx.x;
  int r = blockIdx.x * 4 + (t >> 6);
  int l = t & 63;
  float b1 = pL1[r], b2 = pL2[r], S = pS[r];
  int i1 = pI1[r], i2 = pI2[r];
  #pragma unroll
  for (int c = 1; c < NCS; ++c) {
    size_t o = (size_t)c * NROWS + r;
    float ob1 = pL1[o], ob2 = pL2[o], oS = pS[o];
    int oi1 = pI1[o], oi2 = pI2[o];
    float pb1 = b1;
    ins2(ob1, oi1, b1, i1, b2, i2);
    ins2(ob2, oi2, b1, i1, b2, i2);
    S = S * exp2f(pb1 - b1) + oS * exp2f(ob1 - b1);
  }
  int cand = (l < 32) ? i1 : i2;
  int lo = l & 31;
  const float* zr = zn + (size_t)r * 256;
  const float* wc = wn + (size_t)cand * 256;
  float d = 0.f;
  #pragma unroll
  for (int q = 0; q < 8; ++q) d += zr[lo + q*32] * wc[lo + q*32];
  #pragma unroll
  for (int mask = 1; mask <= 16; mask <<= 1) d += __shfl_xor(d, mask, 64);
  float dOther = __shfl_xor(d, 32, 64);
  if (l == 0) {
    float s1 = w2[i1] - 2.f*d;       // exact, z2 common term dropped
    float s2 = w2[i2] - 2.f*dOther;
    int win = i1;
    if (s2 < s1 || (s2 == s1 && i2 < i1)) win = i2;
    rm[r] = b1; rs[r] = S; ridx[r] = win;
  }
}

// ---- Pass 2 (MFMA): recompute logits; avg_probs + sample entropy ----
__global__ __attribute__((amdgpu_flat_work_group_size(256,256)))
__attribute__((amdgpu_waves_per_eu(2,2))) void k4_pass2(
    const u16* __restrict__ znh, const u16* __restrict__ znl,
    const u16* __restrict__ wnh, const u16* __restrict__ wnl,
    const float* __restrict__ rm, const float* __restrict__ rs,
    float* __restrict__ avgp, float* __restrict__ scal) {
  __shared__ u16 Cbuf[3][2][128*32];
  __shared__ float avgLds[2][128];
  __shared__ float red[256];
  int t = threadIdx.x;
  int rb = blockIdx.x >> 2, cs = blockIdx.x & 3;
  int r0 = rb * 64;
  int w = t >> 6, l = t & 63;
  int wxc = w & 1, wy = w >> 1;
  int g = l >> 4, lr = l & 15;

  bf16x8 bh[2][8], bl[2][8];
  #pragma unroll
  for (int jr = 0; jr < 2; ++jr) {
    size_t rbase = (size_t)(r0 + wy*32 + jr*16 + lr) * 256;
    #pragma unroll
    for (int dc = 0; dc < 8; ++dc) {
      bh[jr][dc] = *(const bf16x8*)&znh[rbase + dc*32 + g*8];
      bl[jr][dc] = *(const bf16x8*)&znl[rbase + dc*32 + g*8];
    }
  }
  float m_[2], invS[2], l2s[2];
  #pragma unroll
  for (int jr = 0; jr < 2; ++jr) {
    int r = r0 + wy*32 + jr*16 + lr;
    float mm = rm[r], ss = rs[r];
    m_[jr] = mm; invS[jr] = 1.f / ss; l2s[jr] = log2f(ss);
  }

  const size_t csbase = (size_t)cs * 2048 * 256;
  auto stage = [&](int s, int b) {
    int dc2 = s & 7;
    int krow = (s >> 3) * 128;
    #pragma unroll
    for (int rnd = 0; rnd < 2; ++rnd) {
      int i = rnd*256 + t;
      int code = i >> 2, q = i & 3;
      size_t go = csbase + (size_t)(krow + code)*256 + dc2*32 + q*8;
      gl_lds16(&wnh[go], &Cbuf[b][0][rnd*2048 + w*512]);
      gl_lds16(&wnl[go], &Cbuf[b][1][rnd*2048 + w*512]);
    }
  };
  DRAIN_VM();
  stage(0, 0);
  stage(1, 1);
  float ent = 0.f;

  for (int kt = 0; kt < 16; ++kt) {
    f32x4 acc[4][2];
    #pragma unroll
    for (int i = 0; i < 4; ++i) { acc[i][0] = (f32x4){0.f,0.f,0.f,0.f}; acc[i][1] = (f32x4){0.f,0.f,0.f,0.f}; }
    #pragma unroll
    for (int dc = 0; dc < 8; ++dc) {
      int s = kt*8 + dc;
      if (s < 127) PHASE_BARRIER_CNT(); else PHASE_BARRIER_ALL();
      if (s + 2 < 128) {
        int bS = s + 2; bS -= (bS/3)*3;
        stage(s + 2, bS);
      }
      int bR = s - (s/3)*3;
      #pragma unroll
      for (int i = 0; i < 4; ++i) {
        int co = (wxc*64 + i*16 + lr)*32 + g*8;
        bf16x8 ah = *(const bf16x8*)&Cbuf[bR][0][co];
        bf16x8 al = *(const bf16x8*)&Cbuf[bR][1][co];
        acc[i][0] = __builtin_amdgcn_mfma_f32_16x16x32_bf16(ah, bh[0][dc], acc[i][0], 0, 0, 0);
        acc[i][1] = __builtin_amdgcn_mfma_f32_16x16x32_bf16(ah, bh[1][dc], acc[i][1], 0, 0, 0);
        acc[i][0] = __builtin_amdgcn_mfma_f32_16x16x32_bf16(ah, bl[0][dc], acc[i][0], 0, 0, 0);
        acc[i][1] = __builtin_amdgcn_mfma_f32_16x16x32_bf16(ah, bl[1][dc], acc[i][1], 0, 0, 0);
        acc[i][0] = __builtin_amdgcn_mfma_f32_16x16x32_bf16(al, bh[0][dc], acc[i][0], 0, 0, 0);
        acc[i][1] = __builtin_amdgcn_mfma_f32_16x16x32_bf16(al, bh[1][dc], acc[i][1], 0, 0, 0);
      }
    }
    int kb = cs*2048 + kt*128;
    float codeAcc[16];
    #pragma unroll
    for (int n = 0; n < 16; ++n) codeAcc[n] = 0.f;
    #pragma unroll
    for (int jr = 0; jr < 2; ++jr) {
      float m = m_[jr], is = invS[jr], l2 = l2s[jr];
      #pragma unroll
      for (int i = 0; i < 4; ++i)
        #pragma unroll
        for (int v = 0; v < 4; ++v) {
          float tt = fmaf(CEXP, acc[i][jr][v], -m);
          float p = exp2f(tt) * is;
          ent -= p * (tt - l2);
          codeAcc[i*4+v] += p;
        }
    }
    #pragma unroll
    for (int n = 0; n < 16; ++n) {
      float s = codeAcc[n];
      s += __shfl_xor(s, 1, 64);
      s += __shfl_xor(s, 2, 64);
      s += __shfl_xor(s, 4, 64);
      s += __shfl_xor(s, 8, 64);
      if (lr == 0) avgLds[wy][wxc*64 + (n>>2)*16 + g*4 + (n&3)] = s;
    }
    LGKM_BARRIER();
    if (t < 128) atomicAdd(&avgp[kb + t], (avgLds[0][t] + avgLds[1][t]) * (1.f/16384.f));
  }
  red[t] = ent;
  __syncthreads();
  for (int s2 = 128; s2; s2 >>= 1) { if (t < s2) red[t] += red[t + s2]; __syncthreads(); }
  if (t == 0) atomicAdd(&scal[1], red[0] * 0.6931471806f);   // exp2-space -> nat
}

// gather q = wn[idx], codebook loss, write z_q channel-first
__global__ __launch_bounds__(256) void k5_gather(const float* __restrict__ zn,
    const float* __restrict__ wn, const int* __restrict__ row_idx,
    float* __restrict__ out_zq, float* __restrict__ scal) {
  __shared__ float tile[256][33];
  __shared__ float red4[4];
  __shared__ float red[256];
  int bh = blockIdx.x, t = threadIdx.x;
  int b = bh >> 5, h = bh & 31;
  float cb = 0.f;
  for (int w = 0; w < 32; ++w) {
    int r = bh*32 + w;
    int idx = row_idx[r];
    float q = wn[(size_t)idx*256 + t];
    float s = q*q;
    #pragma unroll
    for (int mask = 32; mask; mask >>= 1) s += __shfl_xor(s, mask, 64);
    if ((t & 63) == 0) red4[t >> 6] = s;
    __syncthreads();
    float tot = red4[0] + red4[1] + red4[2] + red4[3];
    float inv = 1.f / fmaxf(sqrtf(tot), 1e-6f);
    float zv = zn[(size_t)r*256 + t];
    float d = q*inv - zv;
    cb += d*d;
    tile[t][w] = q;
    __syncthreads();
  }
  red[t] = cb;
  __syncthreads();
  for (int s2 = 128; s2; s2 >>= 1) { if (t < s2) red[t] += red[t+s2]; __syncthreads(); }
  if (t == 0) atomicAdd(&scal[0], red[0]);
  float* ob = out_zq + (size_t)b*256*1024 + (size_t)h*32;
  for (int j = 0; j < 32; ++j) {
    int i = t + j*256; int c = i >> 5, ww = i & 31;
    ob[(size_t)c*1024 + ww] = tile[c][ww];
  }
}

// finalize scalars + emit indices as float
__global__ __launch_bounds__(256) void k6_final(const float* __restrict__ avg_probs,
    const float* __restrict__ scal, const int* __restrict__ row_idx,
    float* __restrict__ out) {
  int t = threadIdx.x;
  if (blockIdx.x < 64) {
    int r = blockIdx.x*256 + t;
    out[4194307 + r] = (float)row_idx[r];
    return;
  }
  __shared__ float red[256];
  float s = 0.f;
  for (int j = 0; j < 32; ++j) {
    float v = avg_probs[t + j*256];
    s -= v * logf(v + 1e-5f);
  }
  red[t] = s;
  __syncthreads();
  for (int q = 128; q; q >>= 1) { if (t < q) red[t] += red[t+q]; __syncthreads(); }
  if (t == 0) {
    float avg_entropy = red[0];
    float sample_entropy = scal[1] * (1.f/16384.f);
    float cb = scal[0] * (1.f/4194304.f);
    out[4194304] = cb;
    out[4194305] = 0.25f * cb;
    out[4194306] = 0.1f * (sample_entropy - avg_entropy);
  }
}

extern "C" void kernel_launch(void* const* d_in, const int* in_sizes, int n_in,
                              void* d_out, int out_size, void* d_ws, size_t ws_size,
                              hipStream_t stream) {
  const float* z   = (const float*)d_in[0];
  const float* emb = (const float*)d_in[1];
  const float* pw  = (const float*)d_in[2];
  const float* pb  = (const float*)d_in[3];
  float* ws  = (float*)d_ws;
  float* out = (float*)d_out;
  float* wn   = ws + OFF_WN;
  float* w2   = ws + OFF_W2;
  float* zn   = ws + OFF_ZN;
  u16*   wnh  = (u16*)(ws + OFF_WNH);
  u16*   wnl  = (u16*)(ws + OFF_WNL);
  u16*   znh  = (u16*)(ws + OFF_ZNH);
  u16*   znl  = (u16*)(ws + OFF_ZNL);
  float* pL1  = ws + OFF_PL1;
  float* pL2  = ws + OFF_PL2;
  float* pS   = ws + OFF_PS;
  int*   pI1  = (int*)(ws + OFF_PI1);
  int*   pI2  = (int*)(ws + OFF_PI2);
  float* rm   = ws + OFF_RM;
  float* rs   = ws + OFF_RS;
  int*   ridx = (int*)(ws + OFF_RIDX);
  float* avgp = ws + OFF_AVGP;
  float* scal = ws + OFF_SCAL;

  k0_init<<<32, 256, 0, stream>>>(ws);
  k1_codebook<<<NCODES, 256, 0, stream>>>(emb, pw, pb, wn, w2, wnh, wnl);
  k2_zn<<<512, 256, 0, stream>>>(z, zn, znh, znl);
  k3_pass1<<<1024, 256, 0, stream>>>(znh, znl, wnh, wnl, pL1, pL2, pS, pI1, pI2);
  k3b_refine<<<NROWS/4, 256, 0, stream>>>(zn, wn, w2, pL1, pL2, pS, pI1, pI2, rm, rs, ridx);
  k4_pass2<<<1024, 256, 0, stream>>>(znh, znl, wnh, wnl, rm, rs, avgp, scal);
  k5_gather<<<512, 256, 0, stream>>>(zn, wn, ridx, out, scal);
  k6_final<<<65, 256, 0, stream>>>(avgp, scal, ridx, out);
}

// Round 12
// 858.575 us; speedup vs baseline: 73.3752x; 1.0025x over previous
//
#include <hip/hip_runtime.h>
#include <math.h>

// Problem constants
#define NROWS 16384      // B*H*W = 16*32*32
#define NCODES 8192
#define DIMS 256
#define NCS 4            // code-slices (2048 codes each); cs = blockIdx&3
#define CEXP 288.5390082f   // 200 * log2(e): logits in exp2-space, y = CEXP*dot

// ws layout (float offsets)
#define OFF_WN   0u          // fp32 wn       8192*256
#define OFF_W2   2097152u    // fp32 w2       8192
#define OFF_ZN   2105344u    // fp32 zn       16384*256
#define OFF_WNH  6299648u    // ushort wn_hi
#define OFF_WNL  7348224u    // ushort wn_lo
#define OFF_ZNH  8396800u    // ushort zn_hi
#define OFF_ZNL  10493952u   // ushort zn_lo
#define OFF_PL1  12591104u   // [4][16384] partial top1 logit (y-space)
#define OFF_PL2  12656640u   // [4][16384] partial top2 logit
#define OFF_PS   12722176u   // [4][16384] partial sum-exp2
#define OFF_PI1  12787712u   // [4][16384] partial top1 idx (int)
#define OFF_PI2  12853248u   // [4][16384] partial top2 idx (int)
#define OFF_RM   12918784u   // 16384 final row max (y-space)
#define OFF_RS   12935168u   // 16384 final row sum-exp2
#define OFF_RIDX 12951552u   // 16384 final exact argmin (int)
#define OFF_AVGP 12967936u   // 8192 avg_probs
#define OFF_SCAL 12976128u   // [0]=cb_sum [1]=ent_sum(nat)

typedef __attribute__((ext_vector_type(8))) short bf16x8;
typedef __attribute__((ext_vector_type(4))) float f32x4;
typedef unsigned short u16;

__device__ __forceinline__ u16 f2bf(float f) {
  unsigned u = __float_as_uint(f);
  u += 0x7fffu + ((u >> 16) & 1u);
  return (u16)(u >> 16);
}
__device__ __forceinline__ float bf2f(u16 s) { return __uint_as_float(((unsigned)s) << 16); }

__device__ __forceinline__ void gl_lds16(const u16* g, u16* l) {
  __builtin_amdgcn_global_load_lds(
      (const __attribute__((address_space(1))) unsigned*)g,
      (__attribute__((address_space(3))) unsigned*)l, 16, 0, 0);
}

#define PHASE_BARRIER_CNT()  asm volatile("s_waitcnt vmcnt(4) lgkmcnt(0)\n\ts_barrier" ::: "memory")
#define PHASE_BARRIER_ALL()  asm volatile("s_waitcnt vmcnt(0) lgkmcnt(0)\n\ts_barrier" ::: "memory")
#define LGKM_BARRIER()       asm volatile("s_waitcnt lgkmcnt(0)\n\ts_barrier" ::: "memory")
#define DRAIN_VM()           asm volatile("s_waitcnt vmcnt(0)" ::: "memory")

// top-2 insert ordered by (value desc, index asc)
__device__ __forceinline__ void ins2(float x, int idx, float& b1, int& i1, float& b2, int& i2) {
  if (x > b1 || (x == b1 && idx < i1)) { b2 = b1; i2 = i1; b1 = x; i1 = idx; }
  else if (x > b2 || (x == b2 && idx < i2)) { b2 = x; i2 = idx; }
}

__global__ __launch_bounds__(256) void k0_init(float* ws) {
  int i = blockIdx.x * 256 + threadIdx.x;
  if (i < NCODES) ws[OFF_AVGP + i] = 0.f;
  if (i < 16) ws[OFF_SCAL + i] = 0.f;
}

// weight = emb @ proj_w^T + b ; wn = normalize; w2 = sum(wn^2); + bf16 hi/lo planes
__global__ __launch_bounds__(256) void k1_codebook(const float* __restrict__ emb,
    const float* __restrict__ pw, const float* __restrict__ pb,
    float* __restrict__ wn, float* __restrict__ w2,
    u16* __restrict__ wnh, u16* __restrict__ wnl) {
  __shared__ float e[256];
  __shared__ float red[256];
  int k = blockIdx.x, t = threadIdx.x;
  e[t] = emb[(size_t)k * 256 + t];
  __syncthreads();
  const float4* prow = reinterpret_cast<const float4*>(pw + (size_t)t * 256);
  float acc = pb[t];
  #pragma unroll 8
  for (int q = 0; q < 64; ++q) {
    float4 p4 = prow[q];
    acc += e[q*4+0]*p4.x + e[q*4+1]*p4.y + e[q*4+2]*p4.z + e[q*4+3]*p4.w;
  }
  red[t] = acc * acc;
  __syncthreads();
  for (int s = 128; s; s >>= 1) { if (t < s) red[t] += red[t+s]; __syncthreads(); }
  float inv = 1.f / fmaxf(sqrtf(red[0]), 1e-6f);
  float v = acc * inv;
  size_t o = (size_t)k*256 + t;
  wn[o] = v;
  u16 hb = f2bf(v); float hf = bf2f(hb);
  wnh[o] = hb; wnl[o] = f2bf(v - hf);
  __syncthreads();
  red[t] = v * v;
  __syncthreads();
  for (int s = 128; s; s >>= 1) { if (t < s) red[t] += red[t+s]; __syncthreads(); }
  if (t == 0) w2[k] = red[0];
}

// zn = normalize over channel dim; zn row-major [row][C] + bf16 hi/lo
__global__ __launch_bounds__(256) void k2_zn(const float* __restrict__ z,
    float* __restrict__ zn, u16* __restrict__ znh, u16* __restrict__ znl) {
  __shared__ float tile[256][33];
  __shared__ float inv[32];
  int bh = blockIdx.x, t = threadIdx.x;
  const float* zb = z + (size_t)(bh >> 5) * (256*1024) + (size_t)(bh & 31) * 32;
  for (int j = 0; j < 32; ++j) {
    int i = t + j*256; int c = i >> 5, w = i & 31;
    tile[c][w] = zb[(size_t)c*1024 + w];
  }
  __syncthreads();
  if (t < 32) {
    float s = 0.f;
    for (int c = 0; c < 256; ++c) { float v = tile[c][t]; s += v*v; }
    inv[t] = 1.f / fmaxf(sqrtf(s), 1e-6f);
  }
  __syncthreads();
  size_t base = (size_t)bh * 32 * 256;
  for (int w = 0; w < 32; ++w) {
    float v = tile[t][w] * inv[w];
    size_t o = base + (size_t)w*256 + t;
    zn[o] = v;
    u16 hb = f2bf(v); float hf = bf2f(hb);
    znh[o] = hb; znl[o] = f2bf(v - hf);
  }
}

// ---- Pass 1 (MFMA): per-row online (max, sum-exp2, per-lane top-2). ----
// y = CEXP*dot (w2 dropped: wn normalized -> w2 == 1 +- 1e-6; shift-invariant;
// exact indices protected by k3b's fp32 re-score WITH w2).
// Split-bf16: hh + hl + lh. T4 ring of 3 LDS bufs, counted vmcnt(4).
// waves_per_eu(2,4): min 2 keeps 256-VGPR floor (anti-spill, R2/R3 lesson);
// max WAS 2 which CAPPED the scheduler at 2 waves/SIMD (R11 occupancy stuck
// at 23% despite LDS fitting 3 blocks/CU). max=4 unlocks the 3rd block.
__global__ __attribute__((amdgpu_flat_work_group_size(256,256)))
__attribute__((amdgpu_waves_per_eu(2,4))) void k3_pass1(
    const u16* __restrict__ znh, const u16* __restrict__ znl,
    const u16* __restrict__ wnh, const u16* __restrict__ wnl,
    float* __restrict__ pL1, float* __restrict__ pL2, float* __restrict__ pS,
    int* __restrict__ pI1, int* __restrict__ pI2) {
  __shared__ u16 Cbuf[3][2][128*32];    // 48 KiB ring
  __shared__ float mrgF[2][2][32][3];
  __shared__ int   mrgI[2][2][32][2];
  int t = threadIdx.x;
  int rb = blockIdx.x >> 2, cs = blockIdx.x & 3;
  int r0 = rb * 64;
  int w = t >> 6, l = t & 63;
  int wxc = w & 1, wy = w >> 1;
  int g = l >> 4, lr = l & 15;

  bf16x8 bh[2][8], bl[2][8];
  #pragma unroll
  for (int jr = 0; jr < 2; ++jr) {
    size_t rbase = (size_t)(r0 + wy*32 + jr*16 + lr) * 256;
    #pragma unroll
    for (int dc = 0; dc < 8; ++dc) {
      bh[jr][dc] = *(const bf16x8*)&znh[rbase + dc*32 + g*8];
      bl[jr][dc] = *(const bf16x8*)&znl[rbase + dc*32 + g*8];
    }
  }

  const size_t csbase = (size_t)cs * 2048 * 256;
  auto stage = [&](int s, int b) {
    int dc2 = s & 7;
    int krow = (s >> 3) * 128;
    #pragma unroll
    for (int rnd = 0; rnd < 2; ++rnd) {
      int i = rnd*256 + t;
      int code = i >> 2, q = i & 3;
      size_t go = csbase + (size_t)(krow + code)*256 + dc2*32 + q*8;
      gl_lds16(&wnh[go], &Cbuf[b][0][rnd*2048 + w*512]);
      gl_lds16(&wnl[go], &Cbuf[b][1][rnd*2048 + w*512]);
    }
  };
  DRAIN_VM();
  stage(0, 0);
  stage(1, 1);

  float b1[2] = {-3.0e38f, -3.0e38f}, b2[2] = {-3.0e38f, -3.0e38f}, Sv[2] = {0.f, 0.f};
  int i1[2] = {0, 0}, i2[2] = {0, 0};   // encoded kt*16+n

  for (int kt = 0; kt < 16; ++kt) {
    f32x4 acc[4][2];
    #pragma unroll
    for (int i = 0; i < 4; ++i) { acc[i][0] = (f32x4){0.f,0.f,0.f,0.f}; acc[i][1] = (f32x4){0.f,0.f,0.f,0.f}; }
    #pragma unroll
    for (int dc = 0; dc < 8; ++dc) {
      int s = kt*8 + dc;
      if (s < 127) PHASE_BARRIER_CNT(); else PHASE_BARRIER_ALL();
      if (s + 2 < 128) {
        int bS = s + 2; bS -= (bS/3)*3;
        stage(s + 2, bS);
      }
      int bR = s - (s/3)*3;
      #pragma unroll
      for (int i = 0; i < 4; ++i) {
        int co = (wxc*64 + i*16 + lr)*32 + g*8;
        bf16x8 ah = *(const bf16x8*)&Cbuf[bR][0][co];
        bf16x8 al = *(const bf16x8*)&Cbuf[bR][1][co];
        acc[i][0] = __builtin_amdgcn_mfma_f32_16x16x32_bf16(ah, bh[0][dc], acc[i][0], 0, 0, 0);
        acc[i][1] = __builtin_amdgcn_mfma_f32_16x16x32_bf16(ah, bh[1][dc], acc[i][1], 0, 0, 0);
        acc[i][0] = __builtin_amdgcn_mfma_f32_16x16x32_bf16(ah, bl[0][dc], acc[i][0], 0, 0, 0);
        acc[i][1] = __builtin_amdgcn_mfma_f32_16x16x32_bf16(ah, bl[1][dc], acc[i][1], 0, 0, 0);
        acc[i][0] = __builtin_amdgcn_mfma_f32_16x16x32_bf16(al, bh[0][dc], acc[i][0], 0, 0, 0);
        acc[i][1] = __builtin_amdgcn_mfma_f32_16x16x32_bf16(al, bh[1][dc], acc[i][1], 0, 0, 0);
      }
    }
    // slim per-kt stats: raw-acc top-2 chain + exp2-space sumexp (lane-local)
    int kb16 = kt * 16;
    #pragma unroll
    for (int jr = 0; jr < 2; ++jr) {
      float xv[16];
      #pragma unroll
      for (int n = 0; n < 16; ++n) xv[n] = acc[n>>2][jr][n&3];
      float ob1 = b1[jr];
      #pragma unroll
      for (int n = 0; n < 16; ++n) {
        float x = xv[n];
        bool c1 = x > b1[jr];
        bool c2 = x > b2[jr];
        float hi = fmaxf(x, b1[jr]);
        float lo = fminf(x, b1[jr]);
        b2[jr] = fmaxf(lo, fminf(hi, b2[jr]));
        i2[jr] = c1 ? i1[jr] : (c2 ? (kb16 + n) : i2[jr]);
        b1[jr] = hi;
        i1[jr] = c1 ? (kb16 + n) : i1[jr];
      }
      float negCm = -CEXP * b1[jr];
      float ts0 = 0.f, ts1 = 0.f;
      #pragma unroll
      for (int n = 0; n < 16; n += 2) {
        ts0 += exp2f(fmaf(CEXP, xv[n],   negCm));
        ts1 += exp2f(fmaf(CEXP, xv[n+1], negCm));
      }
      Sv[jr] = Sv[jr] * exp2f(CEXP * (ob1 - b1[jr])) + (ts0 + ts1);
    }
  }
  // decode indices, convert to y-space, merge lanes (g), then waves (wxc)
  float my[2], y2[2]; int gi1[2], gi2[2];
  #pragma unroll
  for (int jr = 0; jr < 2; ++jr) {
    int e1 = i1[jr], e2 = i2[jr];
    int base = cs*2048 + wxc*64 + g*4;
    gi1[jr] = base + (e1>>4)*128 + ((e1&15)>>2)*16 + (e1&3);
    gi2[jr] = base + (e2>>4)*128 + ((e2&15)>>2)*16 + (e2&3);
    my[jr] = CEXP * b1[jr];
    y2[jr] = CEXP * b2[jr];
    #pragma unroll
    for (int mask = 16; mask <= 32; mask <<= 1) {
      float om  = __shfl_xor(my[jr], mask, 64);
      float oy2 = __shfl_xor(y2[jr], mask, 64);
      float oS  = __shfl_xor(Sv[jr], mask, 64);
      int   o1  = __shfl_xor(gi1[jr], mask, 64);
      int   o2  = __shfl_xor(gi2[jr], mask, 64);
      float pm = my[jr];
      ins2(om,  o1, my[jr], gi1[jr], y2[jr], gi2[jr]);
      ins2(oy2, o2, my[jr], gi1[jr], y2[jr], gi2[jr]);
      Sv[jr] = Sv[jr] * exp2f(pm - my[jr]) + oS * exp2f(om - my[jr]);
    }
  }
  __syncthreads();
  if (g == 0) {
    #pragma unroll
    for (int jr = 0; jr < 2; ++jr) {
      int ri = jr*16 + lr;
      mrgF[wy][wxc][ri][0] = my[jr]; mrgF[wy][wxc][ri][1] = y2[jr]; mrgF[wy][wxc][ri][2] = Sv[jr];
      mrgI[wy][wxc][ri][0] = gi1[jr]; mrgI[wy][wxc][ri][1] = gi2[jr];
    }
  }
  __syncthreads();
  if (t < 64) {
    int wyy = t >> 5, ri = t & 31;
    float m1 = mrgF[wyy][0][ri][0], m2 = mrgF[wyy][0][ri][1], S = mrgF[wyy][0][ri][2];
    int a1 = mrgI[wyy][0][ri][0], a2 = mrgI[wyy][0][ri][1];
    float om1 = mrgF[wyy][1][ri][0], om2 = mrgF[wyy][1][ri][1], oS = mrgF[wyy][1][ri][2];
    int ob1i = mrgI[wyy][1][ri][0], ob2i = mrgI[wyy][1][ri][1];
    float pm = m1;
    ins2(om1, ob1i, m1, a1, m2, a2);
    ins2(om2, ob2i, m1, a1, m2, a2);
    S = S * exp2f(pm - m1) + oS * exp2f(om1 - m1);
    int r = r0 + wyy*32 + ri;
    size_t o = (size_t)cs * NROWS + r;
    pL1[o] = m1; pL2[o] = m2; pS[o] = S;
    pI1[o] = a1; pI2[o] = a2;
  }
}

// merge 4 code-slice partials; exact fp32 re-score of top-2 -> final argmin
__global__ __launch_bounds__(256) void k3b_refine(
    const float* __restrict__ zn, const float* __restrict__ wn, const float* __restrict__ w2,
    const float* __restrict__ pL1, const float* __restrict__ pL2, const float* __restrict__ pS,
    const int* __restrict__ pI1, const int* __restrict__ pI2,
    float* __restrict__ rm, float* __restrict__ rs, int* __restrict__ ridx) {
  int t = threadIdx.x;
  int r = blockIdx.x * 4 + (t >> 6);
  int l = t & 63;
  float b1 = pL1[r], b2 = pL2[r], S = pS[r];
  int i1 = pI1[r], i2 = pI2[r];
  #pragma unroll
  for (int c = 1; c < NCS; ++c) {
    size_t o = (size_t)c * NROWS + r;
    float ob1 = pL1[o], ob2 = pL2[o], oS = pS[o];
    int oi1 = pI1[o], oi2 = pI2[o];
    float pb1 = b1;
    ins2(ob1, oi1, b1, i1, b2, i2);
    ins2(ob2, oi2, b1, i1, b2, i2);
    S = S * exp2f(pb1 - b1) + oS * exp2f(ob1 - b1);
  }
  int cand = (l < 32) ? i1 : i2;
  int lo = l & 31;
  const float* zr = zn + (size_t)r * 256;
  const float* wc = wn + (size_t)cand * 256;
  float d = 0.f;
  #pragma unroll
  for (int q = 0; q < 8; ++q) d += zr[lo + q*32] * wc[lo + q*32];
  #pragma unroll
  for (int mask = 1; mask <= 16; mask <<= 1) d += __shfl_xor(d, mask, 64);
  float dOther = __shfl_xor(d, 32, 64);
  if (l == 0) {
    float s1 = w2[i1] - 2.f*d;       // exact, z2 common term dropped
    float s2 = w2[i2] - 2.f*dOther;
    int win = i1;
    if (s2 < s1 || (s2 == s1 && i2 < i1)) win = i2;
    rm[r] = b1; rs[r] = S; ridx[r] = win;
  }
}

// ---- Pass 2 (MFMA): recompute logits; avg_probs + sample entropy ----
__global__ __attribute__((amdgpu_flat_work_group_size(256,256)))
__attribute__((amdgpu_waves_per_eu(2,4))) void k4_pass2(
    const u16* __restrict__ znh, const u16* __restrict__ znl,
    const u16* __restrict__ wnh, const u16* __restrict__ wnl,
    const float* __restrict__ rm, const float* __restrict__ rs,
    float* __restrict__ avgp, float* __restrict__ scal) {
  __shared__ u16 Cbuf[3][2][128*32];
  __shared__ float avgLds[2][128];
  __shared__ float red[256];
  int t = threadIdx.x;
  int rb = blockIdx.x >> 2, cs = blockIdx.x & 3;
  int r0 = rb * 64;
  int w = t >> 6, l = t & 63;
  int wxc = w & 1, wy = w >> 1;
  int g = l >> 4, lr = l & 15;

  bf16x8 bh[2][8], bl[2][8];
  #pragma unroll
  for (int jr = 0; jr < 2; ++jr) {
    size_t rbase = (size_t)(r0 + wy*32 + jr*16 + lr) * 256;
    #pragma unroll
    for (int dc = 0; dc < 8; ++dc) {
      bh[jr][dc] = *(const bf16x8*)&znh[rbase + dc*32 + g*8];
      bl[jr][dc] = *(const bf16x8*)&znl[rbase + dc*32 + g*8];
    }
  }
  float m_[2], invS[2], l2s[2];
  #pragma unroll
  for (int jr = 0; jr < 2; ++jr) {
    int r = r0 + wy*32 + jr*16 + lr;
    float mm = rm[r], ss = rs[r];
    m_[jr] = mm; invS[jr] = 1.f / ss; l2s[jr] = log2f(ss);
  }

  const size_t csbase = (size_t)cs * 2048 * 256;
  auto stage = [&](int s, int b) {
    int dc2 = s & 7;
    int krow = (s >> 3) * 128;
    #pragma unroll
    for (int rnd = 0; rnd < 2; ++rnd) {
      int i = rnd*256 + t;
      int code = i >> 2, q = i & 3;
      size_t go = csbase + (size_t)(krow + code)*256 + dc2*32 + q*8;
      gl_lds16(&wnh[go], &Cbuf[b][0][rnd*2048 + w*512]);
      gl_lds16(&wnl[go], &Cbuf[b][1][rnd*2048 + w*512]);
    }
  };
  DRAIN_VM();
  stage(0, 0);
  stage(1, 1);
  float ent = 0.f;

  for (int kt = 0; kt < 16; ++kt) {
    f32x4 acc[4][2];
    #pragma unroll
    for (int i = 0; i < 4; ++i) { acc[i][0] = (f32x4){0.f,0.f,0.f,0.f}; acc[i][1] = (f32x4){0.f,0.f,0.f,0.f}; }
    #pragma unroll
    for (int dc = 0; dc < 8; ++dc) {
      int s = kt*8 + dc;
      if (s < 127) PHASE_BARRIER_CNT(); else PHASE_BARRIER_ALL();
      if (s + 2 < 128) {
        int bS = s + 2; bS -= (bS/3)*3;
        stage(s + 2, bS);
      }
      int bR = s - (s/3)*3;
      #pragma unroll
      for (int i = 0; i < 4; ++i) {
        int co = (wxc*64 + i*16 + lr)*32 + g*8;
        bf16x8 ah = *(const bf16x8*)&Cbuf[bR][0][co];
        bf16x8 al = *(const bf16x8*)&Cbuf[bR][1][co];
        acc[i][0] = __builtin_amdgcn_mfma_f32_16x16x32_bf16(ah, bh[0][dc], acc[i][0], 0, 0, 0);
        acc[i][1] = __builtin_amdgcn_mfma_f32_16x16x32_bf16(ah, bh[1][dc], acc[i][1], 0, 0, 0);
        acc[i][0] = __builtin_amdgcn_mfma_f32_16x16x32_bf16(ah, bl[0][dc], acc[i][0], 0, 0, 0);
        acc[i][1] = __builtin_amdgcn_mfma_f32_16x16x32_bf16(ah, bl[1][dc], acc[i][1], 0, 0, 0);
        acc[i][0] = __builtin_amdgcn_mfma_f32_16x16x32_bf16(al, bh[0][dc], acc[i][0], 0, 0, 0);
        acc[i][1] = __builtin_amdgcn_mfma_f32_16x16x32_bf16(al, bh[1][dc], acc[i][1], 0, 0, 0);
      }
    }
    int kb = cs*2048 + kt*128;
    float codeAcc[16];
    #pragma unroll
    for (int n = 0; n < 16; ++n) codeAcc[n] = 0.f;
    #pragma unroll
    for (int jr = 0; jr < 2; ++jr) {
      float m = m_[jr], is = invS[jr], l2 = l2s[jr];
      #pragma unroll
      for (int i = 0; i < 4; ++i)
        #pragma unroll
        for (int v = 0; v < 4; ++v) {
          float tt = fmaf(CEXP, acc[i][jr][v], -m);
          float p = exp2f(tt) * is;
          ent -= p * (tt - l2);
          codeAcc[i*4+v] += p;
        }
    }
    #pragma unroll
    for (int n = 0; n < 16; ++n) {
      float s = codeAcc[n];
      s += __shfl_xor(s, 1, 64);
      s += __shfl_xor(s, 2, 64);
      s += __shfl_xor(s, 4, 64);
      s += __shfl_xor(s, 8, 64);
      if (lr == 0) avgLds[wy][wxc*64 + (n>>2)*16 + g*4 + (n&3)] = s;
    }
    LGKM_BARRIER();
    if (t < 128) atomicAdd(&avgp[kb + t], (avgLds[0][t] + avgLds[1][t]) * (1.f/16384.f));
  }
  red[t] = ent;
  __syncthreads();
  for (int s2 = 128; s2; s2 >>= 1) { if (t < s2) red[t] += red[t + s2]; __syncthreads(); }
  if (t == 0) atomicAdd(&scal[1], red[0] * 0.6931471806f);   // exp2-space -> nat
}

// gather q = wn[idx], codebook loss, write z_q channel-first
__global__ __launch_bounds__(256) void k5_gather(const float* __restrict__ zn,
    const float* __restrict__ wn, const int* __restrict__ row_idx,
    float* __restrict__ out_zq, float* __restrict__ scal) {
  __shared__ float tile[256][33];
  __shared__ float red4[4];
  __shared__ float red[256];
  int bh = blockIdx.x, t = threadIdx.x;
  int b = bh >> 5, h = bh & 31;
  float cb = 0.f;
  for (int w = 0; w < 32; ++w) {
    int r = bh*32 + w;
    int idx = row_idx[r];
    float q = wn[(size_t)idx*256 + t];
    float s = q*q;
    #pragma unroll
    for (int mask = 32; mask; mask >>= 1) s += __shfl_xor(s, mask, 64);
    if ((t & 63) == 0) red4[t >> 6] = s;
    __syncthreads();
    float tot = red4[0] + red4[1] + red4[2] + red4[3];
    float inv = 1.f / fmaxf(sqrtf(tot), 1e-6f);
    float zv = zn[(size_t)r*256 + t];
    float d = q*inv - zv;
    cb += d*d;
    tile[t][w] = q;
    __syncthreads();
  }
  red[t] = cb;
  __syncthreads();
  for (int s2 = 128; s2; s2 >>= 1) { if (t < s2) red[t] += red[t+s2]; __syncthreads(); }
  if (t == 0) atomicAdd(&scal[0], red[0]);
  float* ob = out_zq + (size_t)b*256*1024 + (size_t)h*32;
  for (int j = 0; j < 32; ++j) {
    int i = t + j*256; int c = i >> 5, ww = i & 31;
    ob[(size_t)c*1024 + ww] = tile[c][ww];
  }
}

// finalize scalars + emit indices as float
__global__ __launch_bounds__(256) void k6_final(const float* __restrict__ avg_probs,
    const float* __restrict__ scal, const int* __restrict__ row_idx,
    float* __restrict__ out) {
  int t = threadIdx.x;
  if (blockIdx.x < 64) {
    int r = blockIdx.x*256 + t;
    out[4194307 + r] = (float)row_idx[r];
    return;
  }
  __shared__ float red[256];
  float s = 0.f;
  for (int j = 0; j < 32; ++j) {
    float v = avg_probs[t + j*256];
    s -= v * logf(v + 1e-5f);
  }
  red[t] = s;
  __syncthreads();
  for (int q = 128; q; q >>= 1) { if (t < q) red[t] += red[t+q]; __syncthreads(); }
  if (t == 0) {
    float avg_entropy = red[0];
    float sample_entropy = scal[1] * (1.f/16384.f);
    float cb = scal[0] * (1.f/4194304.f);
    out[4194304] = cb;
    out[4194305] = 0.25f * cb;
    out[4194306] = 0.1f * (sample_entropy - avg_entropy);
  }
}

extern "C" void kernel_launch(void* const* d_in, const int* in_sizes, int n_in,
                              void* d_out, int out_size, void* d_ws, size_t ws_size,
                              hipStream_t stream) {
  const float* z   = (const float*)d_in[0];
  const float* emb = (const float*)d_in[1];
  const float* pw  = (const float*)d_in[2];
  const float* pb  = (const float*)d_in[3];
  float* ws  = (float*)d_ws;
  float* out = (float*)d_out;
  float* wn   = ws + OFF_WN;
  float* w2   = ws + OFF_W2;
  float* zn   = ws + OFF_ZN;
  u16*   wnh  = (u16*)(ws + OFF_WNH);
  u16*   wnl  = (u16*)(ws + OFF_WNL);
  u16*   znh  = (u16*)(ws + OFF_ZNH);
  u16*   znl  = (u16*)(ws + OFF_ZNL);
  float* pL1  = ws + OFF_PL1;
  float* pL2  = ws + OFF_PL2;
  float* pS   = ws + OFF_PS;
  int*   pI1  = (int*)(ws + OFF_PI1);
  int*   pI2  = (int*)(ws + OFF_PI2);
  float* rm   = ws + OFF_RM;
  float* rs   = ws + OFF_RS;
  int*   ridx = (int*)(ws + OFF_RIDX);
  float* avgp = ws + OFF_AVGP;
  float* scal = ws + OFF_SCAL;

  k0_init<<<32, 256, 0, stream>>>(ws);
  k1_codebook<<<NCODES, 256, 0, stream>>>(emb, pw, pb, wn, w2, wnh, wnl);
  k2_zn<<<512, 256, 0, stream>>>(z, zn, znh, znl);
  k3_pass1<<<1024, 256, 0, stream>>>(znh, znl, wnh, wnl, pL1, pL2, pS, pI1, pI2);
  k3b_refine<<<NROWS/4, 256, 0, stream>>>(zn, wn, w2, pL1, pL2, pS, pI1, pI2, rm, rs, ridx);
  k4_pass2<<<1024, 256, 0, stream>>>(znh, znl, wnh, wnl, rm, rs, avgp, scal);
  k5_gather<<<512, 256, 0, stream>>>(zn, wn, ridx, out, scal);
  k6_final<<<65, 256, 0, stream>>>(avgp, scal, ridx, out);
}